// Round 3
// baseline (2313.252 us; speedup 1.0000x reference)
//
#include <hip/hip_runtime.h>
#include <hip/hip_bf16.h>
#include <math.h>

typedef float f32x4_t __attribute__((ext_vector_type(4)));
typedef __bf16 bf16x8_t __attribute__((ext_vector_type(8)));
typedef __bf16 bf16x4_t __attribute__((ext_vector_type(4)));

// ---------------------------------------------------------------------------
// Weight prep: fp32 W[K][N] -> bf16 hi/lo planes, transposed to [N][K].
// LDS 64x64 tile transpose: coalesced reads AND writes (the naive version
// re-fetched each cacheline ~16x). K,N are multiples of 64 for all weights.
// ---------------------------------------------------------------------------
struct WDesc { const float* src; __bf16* hi; __bf16* lo; int K; int N; };
struct WPack { WDesc w[12]; };

__global__ __launch_bounds__(256) void prep_weights_kernel(WPack p) {
  WDesc d = p.w[blockIdx.y];
  const int tilesN = d.N >> 6;
  const int ntiles = (d.K >> 6) * tilesN;
  __shared__ float tile[64][65];
  const int tid = threadIdx.x;
  const int r = tid >> 4, cq = (tid & 15) << 2;   // read: row r(+16i), col quad cq
  const int c = tid >> 4, rq = (tid & 15) << 2;   // write: col c(+16i), row quad rq
  for (int t = blockIdx.x; t < ntiles; t += gridDim.x) {
    const int tk = t / tilesN, tn = t - tk * tilesN;
    const int k0 = tk << 6, n0 = tn << 6;
#pragma unroll
    for (int i = 0; i < 4; i++) {
      const float4 v = *reinterpret_cast<const float4*>(
          &d.src[(size_t)(k0 + r + i * 16) * d.N + n0 + cq]);
      tile[r + i * 16][cq] = v.x; tile[r + i * 16][cq + 1] = v.y;
      tile[r + i * 16][cq + 2] = v.z; tile[r + i * 16][cq + 3] = v.w;
    }
    __syncthreads();
#pragma unroll
    for (int i = 0; i < 4; i++) {
      const int cc = c + i * 16;
      const float v0 = tile[rq][cc], v1 = tile[rq + 1][cc];
      const float v2 = tile[rq + 2][cc], v3 = tile[rq + 3][cc];
      const __bf16 h0 = (__bf16)v0, h1 = (__bf16)v1, h2 = (__bf16)v2, h3 = (__bf16)v3;
      bf16x4_t hv = {h0, h1, h2, h3};
      bf16x4_t lv = {(__bf16)(v0 - (float)h0), (__bf16)(v1 - (float)h1),
                     (__bf16)(v2 - (float)h2), (__bf16)(v3 - (float)h3)};
      *reinterpret_cast<bf16x4_t*>(&d.hi[(size_t)(n0 + cc) * d.K + k0 + rq]) = hv;
      *reinterpret_cast<bf16x4_t*>(&d.lo[(size_t)(n0 + cc) * d.K + k0 + rq]) = lv;
    }
    __syncthreads();
  }
}

// ---------------------------------------------------------------------------
// LayerNorm over D=512, one wave per row
// ---------------------------------------------------------------------------
__global__ __launch_bounds__(256) void ln_kernel(const float* __restrict__ x,
                                                 const float* __restrict__ g,
                                                 const float* __restrict__ bb,
                                                 float* __restrict__ y) {
  const int row = blockIdx.x * 4 + (threadIdx.x >> 6);
  const int lane = threadIdx.x & 63;
  const float* xr = x + (size_t)row * 512;
  float4 a = *reinterpret_cast<const float4*>(&xr[lane * 8]);
  float4 b4 = *reinterpret_cast<const float4*>(&xr[lane * 8 + 4]);
  float v[8] = {a.x, a.y, a.z, a.w, b4.x, b4.y, b4.z, b4.w};
  float s = 0.f;
#pragma unroll
  for (int j = 0; j < 8; j++) s += v[j];
#pragma unroll
  for (int off = 1; off < 64; off <<= 1) s += __shfl_xor(s, off);
  const float mean = s * (1.f / 512.f);
  float sq = 0.f;
#pragma unroll
  for (int j = 0; j < 8; j++) { v[j] -= mean; sq += v[j] * v[j]; }
#pragma unroll
  for (int off = 1; off < 64; off <<= 1) sq += __shfl_xor(sq, off);
  const float inv = rsqrtf(sq * (1.f / 512.f) + 1e-6f);
  float o[8];
#pragma unroll
  for (int j = 0; j < 8; j++) o[j] = v[j] * inv * g[lane * 8 + j] + bb[lane * 8 + j];
  float* yr = y + (size_t)row * 512;
  *reinterpret_cast<float4*>(&yr[lane * 8]) = make_float4(o[0], o[1], o[2], o[3]);
  *reinterpret_cast<float4*>(&yr[lane * 8 + 4]) = make_float4(o[4], o[5], o[6], o[7]);
}

// ---------------------------------------------------------------------------
// Split-bf16 MFMA GEMM: C[M,N] = [A0|A1][M,K](f32) * B[K,N] + bias.
// B pre-split as Bh/Bl [N][K] bf16. Tile 128x128, BK=32, 256 threads.
// A columns >= ksplit come from A1 (col - ksplit), same lda.
// EPI: 0 plain, 1 relu, 2 sigmoid-gate(e0=attn,e1=ctx,e2=residual), 3 +e0
// ---------------------------------------------------------------------------
template <int EPI>
__global__ __launch_bounds__(256, 2) void gemm_kernel(
    const float* __restrict__ A0, const float* __restrict__ A1, int lda, int ksplit,
    const __bf16* __restrict__ Bh, const __bf16* __restrict__ Bl,
    const float* __restrict__ bias,
    float* __restrict__ C, int ldc,
    int M, int N, int K,
    const float* __restrict__ e0, const float* __restrict__ e1,
    const float* __restrict__ e2) {
  __shared__ __bf16 Ah[128][40];
  __shared__ __bf16 Al[128][40];
  __shared__ __bf16 Bsh[128][40];
  __shared__ __bf16 Bsl[128][40];
  const int tid = threadIdx.x;
  const int brow = blockIdx.y * 128, bcol = blockIdx.x * 128;
  const int wave = tid >> 6, lane = tid & 63;
  const int wr = (wave >> 1) * 64, wc = (wave & 1) * 64;
  const int lr = lane & 15, lk = (lane >> 4) * 8;
  f32x4_t acc[4][4] = {};

  for (int k0 = 0; k0 < K; k0 += 32) {
    __syncthreads();
    // stage A with on-the-fly hi/lo split (split-source aware)
#pragma unroll
    for (int i = 0; i < 4; i++) {
      const int fi = i * 256 + tid;        // 1024 float4 chunks = 128r x 8
      const int r = fi >> 3, cq = (fi & 7) << 2;
      const float* Ap = A0;
      int kc = k0 + cq;
      if (kc >= ksplit) { Ap = A1; kc -= ksplit; }
      const float4 v = *reinterpret_cast<const float4*>(&Ap[(size_t)(brow + r) * lda + kc]);
      const __bf16 h0 = (__bf16)v.x, h1 = (__bf16)v.y, h2 = (__bf16)v.z, h3 = (__bf16)v.w;
      bf16x4_t hv = {h0, h1, h2, h3};
      bf16x4_t lv = {(__bf16)(v.x - (float)h0), (__bf16)(v.y - (float)h1),
                     (__bf16)(v.z - (float)h2), (__bf16)(v.w - (float)h3)};
      *reinterpret_cast<bf16x4_t*>(&Ah[r][cq]) = hv;
      *reinterpret_cast<bf16x4_t*>(&Al[r][cq]) = lv;
    }
    // stage B (already bf16 hi/lo, [N][K])
#pragma unroll
    for (int i = 0; i < 4; i++) {
      const int fi = i * 256 + tid;
      const int r = fi >> 3, cq = (fi & 7) << 2;
      *reinterpret_cast<bf16x4_t*>(&Bsh[r][cq]) =
          *reinterpret_cast<const bf16x4_t*>(&Bh[(size_t)(bcol + r) * K + k0 + cq]);
      *reinterpret_cast<bf16x4_t*>(&Bsl[r][cq]) =
          *reinterpret_cast<const bf16x4_t*>(&Bl[(size_t)(bcol + r) * K + k0 + cq]);
    }
    __syncthreads();
    bf16x8_t af[4], alf[4], bfh[4], bfl[4];
#pragma unroll
    for (int m = 0; m < 4; m++) {
      af[m]  = *reinterpret_cast<const bf16x8_t*>(&Ah[wr + m * 16 + lr][lk]);
      alf[m] = *reinterpret_cast<const bf16x8_t*>(&Al[wr + m * 16 + lr][lk]);
    }
#pragma unroll
    for (int n = 0; n < 4; n++) {
      bfh[n] = *reinterpret_cast<const bf16x8_t*>(&Bsh[wc + n * 16 + lr][lk]);
      bfl[n] = *reinterpret_cast<const bf16x8_t*>(&Bsl[wc + n * 16 + lr][lk]);
    }
#pragma unroll
    for (int m = 0; m < 4; m++)
#pragma unroll
      for (int n = 0; n < 4; n++) {
        acc[m][n] = __builtin_amdgcn_mfma_f32_16x16x32_bf16(af[m], bfh[n], acc[m][n], 0, 0, 0);
        acc[m][n] = __builtin_amdgcn_mfma_f32_16x16x32_bf16(af[m], bfl[n], acc[m][n], 0, 0, 0);
        acc[m][n] = __builtin_amdgcn_mfma_f32_16x16x32_bf16(alf[m], bfh[n], acc[m][n], 0, 0, 0);
      }
  }

#pragma unroll
  for (int m = 0; m < 4; m++) {
#pragma unroll
    for (int n = 0; n < 4; n++) {
#pragma unroll
      for (int r = 0; r < 4; r++) {
        const int row = brow + wr + m * 16 + (lane >> 4) * 4 + r;
        const int col = bcol + wc + n * 16 + lr;
        float v = acc[m][n][r] + bias[col];
        if constexpr (EPI == 1) {
          v = fmaxf(v, 0.f);
        } else if constexpr (EPI == 2) {
          const float z = 1.f / (1.f + expf(-v));
          const float a = e0[(size_t)row * 512 + col];
          const float c = e1[(size_t)row * 512 + col];
          v = z * a + (1.f - z) * c + e2[(size_t)row * 512 + col];
        } else if constexpr (EPI == 3) {
          v += e0[(size_t)row * 512 + col];
        }
        C[(size_t)row * ldc + col] = v;
      }
    }
  }
}

// ---------------------------------------------------------------------------
// Self-attention, flash-style. Block = (b, h, 64-row q tile), 256 threads.
// ---------------------------------------------------------------------------
__global__ __launch_bounds__(256) void sa_attn_kernel(
    const float* __restrict__ Q, const float* __restrict__ K,
    const float* __restrict__ V, const int* __restrict__ mask,
    float* __restrict__ O) {
  __shared__ float qs[64][67];
  __shared__ float ks[64][67];
  __shared__ float vs[64][67];
  const int tid = threadIdx.x;
  const int b = blockIdx.z, h = blockIdx.y, q0 = blockIdx.x * 64;
  const int ty = tid >> 4, tx = tid & 15;
#pragma unroll
  for (int i = 0; i < 4; i++) {
    const int fi = i * 256 + tid;
    const int r = fi >> 4, dq = (fi & 15) << 2;
    const float4 v = *reinterpret_cast<const float4*>(&Q[((size_t)(b * 512 + q0 + r)) * 512 + h * 64 + dq]);
    qs[r][dq] = v.x; qs[r][dq + 1] = v.y; qs[r][dq + 2] = v.z; qs[r][dq + 3] = v.w;
  }
  float m[4], l[4], o[4][4];
#pragma unroll
  for (int i = 0; i < 4; i++) {
    m[i] = -INFINITY; l[i] = 0.f;
#pragma unroll
    for (int j = 0; j < 4; j++) o[i][j] = 0.f;
  }
  for (int kt = 0; kt < 8; kt++) {
    const int k0 = kt * 64;
    __syncthreads();
#pragma unroll
    for (int i = 0; i < 4; i++) {
      const int fi = i * 256 + tid;
      const int r = fi >> 4, dq = (fi & 15) << 2;
      const float4 kv = *reinterpret_cast<const float4*>(&K[((size_t)(b * 512 + k0 + r)) * 512 + h * 64 + dq]);
      ks[r][dq] = kv.x; ks[r][dq + 1] = kv.y; ks[r][dq + 2] = kv.z; ks[r][dq + 3] = kv.w;
      const float4 vv = *reinterpret_cast<const float4*>(&V[((size_t)(b * 512 + k0 + r)) * 512 + h * 64 + dq]);
      vs[r][dq] = vv.x; vs[r][dq + 1] = vv.y; vs[r][dq + 2] = vv.z; vs[r][dq + 3] = vv.w;
    }
    __syncthreads();
    float s[4][4] = {};
#pragma unroll 8
    for (int d = 0; d < 64; d++) {
      float qv[4], kv[4];
#pragma unroll
      for (int i = 0; i < 4; i++) qv[i] = qs[ty * 4 + i][d];
#pragma unroll
      for (int j = 0; j < 4; j++) kv[j] = ks[tx * 4 + j][d];
#pragma unroll
      for (int i = 0; i < 4; i++)
#pragma unroll
        for (int j = 0; j < 4; j++) s[i][j] += qv[i] * kv[j];
    }
    float scale[4];
#pragma unroll
    for (int i = 0; i < 4; i++) {
      const int qi = q0 + ty * 4 + i;
      const int4 mv = *reinterpret_cast<const int4*>(&mask[((size_t)b * 512 + qi) * 512 + k0 + tx * 4]);
      s[i][0] = mv.x ? -1e18f : s[i][0] * 0.125f;
      s[i][1] = mv.y ? -1e18f : s[i][1] * 0.125f;
      s[i][2] = mv.z ? -1e18f : s[i][2] * 0.125f;
      s[i][3] = mv.w ? -1e18f : s[i][3] * 0.125f;
      float mx = fmaxf(fmaxf(s[i][0], s[i][1]), fmaxf(s[i][2], s[i][3]));
#pragma unroll
      for (int off = 1; off <= 8; off <<= 1) mx = fmaxf(mx, __shfl_xor(mx, off));
      const float mnew = fmaxf(m[i], mx);
      float rs = 0.f;
#pragma unroll
      for (int j = 0; j < 4; j++) { const float p = expf(s[i][j] - mnew); s[i][j] = p; rs += p; }
#pragma unroll
      for (int off = 1; off <= 8; off <<= 1) rs += __shfl_xor(rs, off);
      scale[i] = expf(m[i] - mnew);
      l[i] = l[i] * scale[i] + rs;
      m[i] = mnew;
    }
    __syncthreads();  // all lanes done reading ks before overwrite with P
#pragma unroll
    for (int i = 0; i < 4; i++)
#pragma unroll
      for (int j = 0; j < 4; j++) ks[ty * 4 + i][tx * 4 + j] = s[i][j];
#pragma unroll
    for (int i = 0; i < 4; i++)
#pragma unroll
      for (int j = 0; j < 4; j++) o[i][j] *= scale[i];
    __syncthreads();
#pragma unroll 8
    for (int kk = 0; kk < 64; kk++) {
      float pv[4], vv[4];
#pragma unroll
      for (int i = 0; i < 4; i++) pv[i] = ks[ty * 4 + i][kk];
#pragma unroll
      for (int j = 0; j < 4; j++) vv[j] = vs[kk][tx * 4 + j];
#pragma unroll
      for (int i = 0; i < 4; i++)
#pragma unroll
        for (int j = 0; j < 4; j++) o[i][j] += pv[i] * vv[j];
    }
  }
#pragma unroll
  for (int i = 0; i < 4; i++) {
    const float inv = 1.f / l[i];
    const float4 ov = make_float4(o[i][0] * inv, o[i][1] * inv, o[i][2] * inv, o[i][3] * inv);
    *reinterpret_cast<float4*>(&O[((size_t)(b * 512 + q0 + ty * 4 + i)) * 512 + h * 64 + tx * 4]) = ov;
  }
}

// ---------------------------------------------------------------------------
// Cross-attention for a 16-chain chunk. Block = (32 queries x 8 heads),
// grid (S/32, 16). Q deduped via chain_map. Output ctxA [16*512, 512].
// ---------------------------------------------------------------------------
__global__ __launch_bounds__(256) void ca_attn_kernel(
    const float* __restrict__ Qbase, const float* __restrict__ Kc,
    const float* __restrict__ Vc, const int* __restrict__ chain_map,
    const int* __restrict__ chain_mask, float* __restrict__ O, int c0) {
  __shared__ float ks[12][512];
  __shared__ float vs[12][512];
  const int tid = threadIdx.x;
  const int cl = blockIdx.y, c = c0 + cl, s0 = blockIdx.x * 32;
#pragma unroll
  for (int i = 0; i < 6; i++) {
    const int fi = i * 256 + tid;          // 1536 float4 per array
    const int lrow = fi >> 7, dq = (fi & 127) << 2;
    *reinterpret_cast<float4*>(&ks[lrow][dq]) =
        *reinterpret_cast<const float4*>(&Kc[((size_t)c * 12 + lrow) * 512 + dq]);
    *reinterpret_cast<float4*>(&vs[lrow][dq]) =
        *reinterpret_cast<const float4*>(&Vc[((size_t)c * 12 + lrow) * 512 + dq]);
  }
  __syncthreads();
  const int h = tid >> 5, sl = tid & 31;
  const int s = s0 + sl;
  const int bq = chain_map[c];
  const float* qrow = &Qbase[((size_t)(bq * 512 + s)) * 512 + h * 64];
  float4 q4[16];
#pragma unroll
  for (int i = 0; i < 16; i++) q4[i] = *reinterpret_cast<const float4*>(&qrow[i * 4]);
  const int* mrow = &chain_mask[((size_t)(c * 512 + s)) * 12];
  float sc[12];
  float mx = -INFINITY;
#pragma unroll
  for (int lI = 0; lI < 12; lI++) {
    float acc = 0.f;
#pragma unroll
    for (int i = 0; i < 16; i++) {
      const float4 kv = *reinterpret_cast<const float4*>(&ks[lI][h * 64 + i * 4]);
      acc += q4[i].x * kv.x + q4[i].y * kv.y + q4[i].z * kv.z + q4[i].w * kv.w;
    }
    acc *= 0.125f;
    if (mrow[lI]) acc = -1e18f;
    sc[lI] = acc;
    mx = fmaxf(mx, acc);
  }
  float sum = 0.f;
#pragma unroll
  for (int lI = 0; lI < 12; lI++) { sc[lI] = expf(sc[lI] - mx); sum += sc[lI]; }
  const float inv = 1.f / sum;
  float* orow = &O[((size_t)(cl * 512 + s)) * 512 + h * 64];
#pragma unroll
  for (int dq = 0; dq < 16; dq++) {
    float4 ov = make_float4(0.f, 0.f, 0.f, 0.f);
#pragma unroll
    for (int lI = 0; lI < 12; lI++) {
      const float4 vv = *reinterpret_cast<const float4*>(&vs[lI][h * 64 + dq * 4]);
      ov.x += sc[lI] * vv.x; ov.y += sc[lI] * vv.y;
      ov.z += sc[lI] * vv.z; ov.w += sc[lI] * vv.w;
    }
    ov.x *= inv; ov.y *= inv; ov.z *= inv; ov.w *= inv;
    *reinterpret_cast<float4*>(&orow[dq * 4]) = ov;
  }
}

// ---------------------------------------------------------------------------
// Running segment-max over a 16-chain chunk. MODE: 0 first, 1 mid, 2 last.
// grid (S, B). ctxB is this chunk's wo-output [16*512,512].
// ---------------------------------------------------------------------------
template <int MODE>
__global__ __launch_bounds__(256) void agg_update_kernel(
    const float* __restrict__ ctxB, const int* __restrict__ chain_map,
    const int* __restrict__ chain_mask, float* __restrict__ ctx_ctx, int c0) {
  const int s = blockIdx.x, b = blockIdx.y, tid = threadIdx.x;
  const size_t orow = ((size_t)(b * 512 + s)) * 512;
  float v0 = -INFINITY, v1 = -INFINITY;
  if (MODE != 0) { v0 = ctx_ctx[orow + tid]; v1 = ctx_ctx[orow + 256 + tid]; }
  for (int i = 0; i < 16; i++) {
    const int c = c0 + i;
    if (chain_map[c] == b && chain_mask[((size_t)(c * 512 + s)) * 12] != 0) {
      const float* row = &ctxB[((size_t)(i * 512 + s)) * 512];
      v0 = fmaxf(v0, row[tid]);
      v1 = fmaxf(v1, row[tid + 256]);
    }
  }
  if (MODE == 2) {
    if (v0 + 1.f == v0) v0 = 0.f;   // zero out -inf (matches out+1==out)
    if (v1 + 1.f == v1) v1 = 0.f;
  }
  ctx_ctx[orow + tid] = v0;
  ctx_ctx[orow + 256 + tid] = v1;
}

// ---------------------------------------------------------------------------
// Host launch
// ---------------------------------------------------------------------------
extern "C" void kernel_launch(void* const* d_in, const int* in_sizes, int n_in,
                              void* d_out, int out_size, void* d_ws, size_t ws_size,
                              hipStream_t stream) {
  const float* inputs     = (const float*)d_in[0];
  const int*   attn_mask  = (const int*)d_in[1];
  const int*   chain_map  = (const int*)d_in[2];
  const float* span       = (const float*)d_in[3];
  const int*   chain_mask = (const int*)d_in[4];
  const float* ln_g = (const float*)d_in[5];
  const float* ln_b = (const float*)d_in[6];
  const float* sa_bq = (const float*)d_in[8];
  const float* sa_bk = (const float*)d_in[10];
  const float* sa_bv = (const float*)d_in[12];
  const float* sa_bo = (const float*)d_in[14];
  const float* lc_b  = (const float*)d_in[16];
  const float* ca_bq = (const float*)d_in[18];
  const float* ca_bk = (const float*)d_in[20];
  const float* ca_bv = (const float*)d_in[22];
  const float* ca_bo = (const float*)d_in[24];
  const float* g_b   = (const float*)d_in[26];
  const float* ff_ln_g = (const float*)d_in[27];
  const float* ff_ln_b = (const float*)d_in[28];
  const float* ff_b1 = (const float*)d_in[30];
  const float* ff_b2 = (const float*)d_in[32];

  char* ws = (char*)d_ws;
  size_t off = 0;
  auto alloc = [&](size_t bytes) -> void* {
    off = (off + 255) & ~(size_t)255;
    void* p = ws + off;
    off += bytes;
    return p;
  };

  // weight prep targets: 12 weights, hi+lo planes each, [N][K] bf16
  const int widx[12] = {7, 9, 11, 13, 15, 17, 19, 21, 23, 25, 29, 31};
  const int wK[12]   = {512, 512, 512, 512, 768, 512, 512, 512, 512, 1024, 512, 2048};
  const int wN[12]   = {512, 512, 512, 512, 512, 512, 512, 512, 512, 512, 2048, 512};
  WPack pack;
  __bf16* WH[12];
  __bf16* WL[12];
  for (int i = 0; i < 12; i++) {
    const size_t el = (size_t)wK[i] * wN[i];
    WH[i] = (__bf16*)alloc(el * 2);
    WL[i] = (__bf16*)alloc(el * 2);
    pack.w[i] = {(const float*)d_in[widx[i]], WH[i], WL[i], wK[i], wN[i]};
  }

  // Region plan (16.78 MB each for [8192,512] f32):
  //  R1: x_norm -> attn_ctx
  //  R2: sa_q -> ca_q -> out1
  //  R3: sa_k -> ctxA(16 chains) -> inter (with R4)
  //  R4: sa_v -> ctxB            -> inter (cont.)
  //  R5: sa_ctx -> ctx_ctx -> y
  //  R6: emb / k_ca / v_ca
  const size_t SZ_BSD = (size_t)8192 * 512 * 4;
  float* R1 = (float*)alloc(SZ_BSD);
  float* R2 = (float*)alloc(SZ_BSD);
  float* R3 = (float*)alloc(SZ_BSD);
  float* R4 = (float*)alloc(SZ_BSD);
  float* R5 = (float*)alloc(SZ_BSD);
  float* emb  = (float*)alloc((size_t)1536 * 512 * 4);
  float* k_ca = (float*)alloc((size_t)1536 * 512 * 4);
  float* v_ca = (float*)alloc((size_t)1536 * 512 * 4);
  if (ws_size < off) return;   // workspace too small: fail loudly, not fault

  float* x_norm   = R1;  float* attn_ctx = R1;
  float* sa_q     = R2;  float* ca_q     = R2;  float* out1 = R2;
  float* sa_k     = R3;  float* ctxA     = R3;  float* interc = R3;  // spans R3+R4
  float* sa_v     = R4;  float* ctxB     = R4;
  float* sa_ctx   = R5;  float* ctx_ctx  = R5;  float* y    = R5;
  float* out = (float*)d_out;
  const int KBIG = 1 << 30;

  auto gemm = [&](int EPI, const float* A0, const float* A1, int lda, int ksplit,
                  int wi, const float* bias, float* C, int ldc,
                  int M, int N, int K,
                  const float* e0, const float* e1, const float* e2) {
    dim3 grid(N / 128, M / 128);
    switch (EPI) {
      case 0: gemm_kernel<0><<<grid, 256, 0, stream>>>(A0, A1, lda, ksplit, WH[wi], WL[wi], bias, C, ldc, M, N, K, e0, e1, e2); break;
      case 1: gemm_kernel<1><<<grid, 256, 0, stream>>>(A0, A1, lda, ksplit, WH[wi], WL[wi], bias, C, ldc, M, N, K, e0, e1, e2); break;
      case 2: gemm_kernel<2><<<grid, 256, 0, stream>>>(A0, A1, lda, ksplit, WH[wi], WL[wi], bias, C, ldc, M, N, K, e0, e1, e2); break;
      case 3: gemm_kernel<3><<<grid, 256, 0, stream>>>(A0, A1, lda, ksplit, WH[wi], WL[wi], bias, C, ldc, M, N, K, e0, e1, e2); break;
    }
  };

  prep_weights_kernel<<<dim3(64, 12), 256, 0, stream>>>(pack);
  ln_kernel<<<2048, 256, 0, stream>>>(inputs, ln_g, ln_b, x_norm);

  // self-attention
  gemm(0, x_norm, nullptr, 512, KBIG, 0, sa_bq, sa_q, 512, 8192, 512, 512, 0, 0, 0);
  gemm(0, x_norm, nullptr, 512, KBIG, 1, sa_bk, sa_k, 512, 8192, 512, 512, 0, 0, 0);
  gemm(0, x_norm, nullptr, 512, KBIG, 2, sa_bv, sa_v, 512, 8192, 512, 512, 0, 0, 0);
  sa_attn_kernel<<<dim3(8, 8, 16), 256, 0, stream>>>(sa_q, sa_k, sa_v, attn_mask, sa_ctx);
  // ca_q before sa_wo so R1 (x_norm) can be overwritten by attn_ctx
  gemm(0, x_norm, nullptr, 512, KBIG, 5, ca_bq, ca_q, 512, 8192, 512, 512, 0, 0, 0);
  gemm(0, sa_ctx, nullptr, 512, KBIG, 3, sa_bo, attn_ctx, 512, 8192, 512, 512, 0, 0, 0);

  // cross-attention K/V precompute
  gemm(0, span, nullptr, 768, KBIG, 4, lc_b, emb, 512, 1536, 512, 768, 0, 0, 0);
  gemm(0, emb, nullptr, 512, KBIG, 6, ca_bk, k_ca, 512, 1536, 512, 512, 0, 0, 0);
  gemm(0, emb, nullptr, 512, KBIG, 7, ca_bv, v_ca, 512, 1536, 512, 512, 0, 0, 0);

  // CA in 8 chunks of 16 chains; running segment-max into ctx_ctx
  for (int ch = 0; ch < 8; ch++) {
    const int c0 = ch * 16;
    ca_attn_kernel<<<dim3(16, 16), 256, 0, stream>>>(ca_q, k_ca, v_ca, chain_map, chain_mask, ctxA, c0);
    gemm(0, ctxA, nullptr, 512, KBIG, 8, ca_bo, ctxB, 512, 8192, 512, 512, 0, 0, 0);
    if (ch == 0)      agg_update_kernel<0><<<dim3(512, 16), 256, 0, stream>>>(ctxB, chain_map, chain_mask, ctx_ctx, c0);
    else if (ch == 7) agg_update_kernel<2><<<dim3(512, 16), 256, 0, stream>>>(ctxB, chain_map, chain_mask, ctx_ctx, c0);
    else              agg_update_kernel<1><<<dim3(512, 16), 256, 0, stream>>>(ctxB, chain_map, chain_mask, ctx_ctx, c0);
  }

  // gate: A = [attn_ctx | ctx_ctx], epilogue z*a+(1-z)*c+inputs
  gemm(2, attn_ctx, ctx_ctx, 512, 512, 9, g_b, out1, 512, 8192, 512, 1024,
       attn_ctx, ctx_ctx, inputs);

  // feed-forward, 2 chunks of 4096 rows (inter reuses R3+R4)
  ln_kernel<<<2048, 256, 0, stream>>>(out1, ff_ln_g, ff_ln_b, y);
  for (int r0 = 0; r0 < 8192; r0 += 4096) {
    gemm(1, y + (size_t)r0 * 512, nullptr, 512, KBIG, 10, ff_b1, interc, 2048,
         4096, 2048, 512, 0, 0, 0);
    gemm(3, interc, nullptr, 2048, KBIG, 11, ff_b2, out + (size_t)r0 * 512, 512,
         4096, 512, 2048, out1 + (size_t)r0 * 512, 0, 0);
  }
}

// Round 5
// 1196.494 us; speedup vs baseline: 1.9334x; 1.9334x over previous
//
#include <hip/hip_runtime.h>
#include <hip/hip_bf16.h>
#include <math.h>

typedef float f32x4_t __attribute__((ext_vector_type(4)));
typedef __bf16 bf16x8_t __attribute__((ext_vector_type(8)));
typedef __bf16 bf16x4_t __attribute__((ext_vector_type(4)));

__device__ __forceinline__ void gload16(const void* g, void* l) {
  __builtin_amdgcn_global_load_lds((const __attribute__((address_space(1))) void*)g,
                                   (__attribute__((address_space(3))) void*)l, 16, 0, 0);
}

// ---------------------------------------------------------------------------
// Weight prep: fp32 W[K][N] -> bf16 hi/lo planes, transposed to [N][K].
// LDS 64x64 tile transpose, coalesced both sides.
// ---------------------------------------------------------------------------
struct WDesc { const float* src; __bf16* hi; __bf16* lo; int K; int N; };
struct WPack { WDesc w[12]; };

__global__ __launch_bounds__(256) void prep_weights_kernel(WPack p) {
  WDesc d = p.w[blockIdx.y];
  const int tilesN = d.N >> 6;
  const int ntiles = (d.K >> 6) * tilesN;
  __shared__ float tile[64][65];
  const int tid = threadIdx.x;
  const int r = tid >> 4, cq = (tid & 15) << 2;
  const int c = tid >> 4, rq = (tid & 15) << 2;
  for (int t = blockIdx.x; t < ntiles; t += gridDim.x) {
    const int tk = t / tilesN, tn = t - tk * tilesN;
    const int k0 = tk << 6, n0 = tn << 6;
#pragma unroll
    for (int i = 0; i < 4; i++) {
      const float4 v = *reinterpret_cast<const float4*>(
          &d.src[(size_t)(k0 + r + i * 16) * d.N + n0 + cq]);
      tile[r + i * 16][cq] = v.x; tile[r + i * 16][cq + 1] = v.y;
      tile[r + i * 16][cq + 2] = v.z; tile[r + i * 16][cq + 3] = v.w;
    }
    __syncthreads();
#pragma unroll
    for (int i = 0; i < 4; i++) {
      const int cc = c + i * 16;
      const float v0 = tile[rq][cc], v1 = tile[rq + 1][cc];
      const float v2 = tile[rq + 2][cc], v3 = tile[rq + 3][cc];
      const __bf16 h0 = (__bf16)v0, h1 = (__bf16)v1, h2 = (__bf16)v2, h3 = (__bf16)v3;
      bf16x4_t hv = {h0, h1, h2, h3};
      bf16x4_t lv = {(__bf16)(v0 - (float)h0), (__bf16)(v1 - (float)h1),
                     (__bf16)(v2 - (float)h2), (__bf16)(v3 - (float)h3)};
      *reinterpret_cast<bf16x4_t*>(&d.hi[(size_t)(n0 + cc) * d.K + k0 + rq]) = hv;
      *reinterpret_cast<bf16x4_t*>(&d.lo[(size_t)(n0 + cc) * d.K + k0 + rq]) = lv;
    }
    __syncthreads();
  }
}

__global__ __launch_bounds__(256) void bias_cat_kernel(
    const float* __restrict__ b0, const float* __restrict__ b1,
    const float* __restrict__ b2, const float* __restrict__ b3,
    float* __restrict__ out) {
  const int t = blockIdx.x * 256 + threadIdx.x;   // grid 8 -> 2048
  const float* s = t < 512 ? b0 : t < 1024 ? b1 : t < 1536 ? b2 : b3;
  out[t] = s[t & 511];
}

// fp32 -> hi/lo bf16 planes, float4-vectorized (for span_embeddings)
__global__ __launch_bounds__(256) void split_kernel(
    const float* __restrict__ x, __bf16* __restrict__ h, __bf16* __restrict__ l, int nq) {
  const int i = blockIdx.x * 256 + threadIdx.x;
  if (i >= nq) return;
  const float4 v = reinterpret_cast<const float4*>(x)[i];
  const __bf16 h0 = (__bf16)v.x, h1 = (__bf16)v.y, h2 = (__bf16)v.z, h3 = (__bf16)v.w;
  bf16x4_t hv = {h0, h1, h2, h3};
  bf16x4_t lv = {(__bf16)(v.x - (float)h0), (__bf16)(v.y - (float)h1),
                 (__bf16)(v.z - (float)h2), (__bf16)(v.w - (float)h3)};
  reinterpret_cast<bf16x4_t*>(h)[i] = hv;
  reinterpret_cast<bf16x4_t*>(l)[i] = lv;
}

// ---------------------------------------------------------------------------
// LayerNorm over D=512, one wave per row, emits hi/lo bf16 planes
// ---------------------------------------------------------------------------
__global__ __launch_bounds__(256) void ln_split_kernel(
    const float* __restrict__ x, const float* __restrict__ g,
    const float* __restrict__ bb, __bf16* __restrict__ yh, __bf16* __restrict__ yl) {
  const int row = blockIdx.x * 4 + (threadIdx.x >> 6);
  const int lane = threadIdx.x & 63;
  const float* xr = x + (size_t)row * 512;
  float4 a = *reinterpret_cast<const float4*>(&xr[lane * 8]);
  float4 b4 = *reinterpret_cast<const float4*>(&xr[lane * 8 + 4]);
  float v[8] = {a.x, a.y, a.z, a.w, b4.x, b4.y, b4.z, b4.w};
  float s = 0.f;
#pragma unroll
  for (int j = 0; j < 8; j++) s += v[j];
#pragma unroll
  for (int off = 1; off < 64; off <<= 1) s += __shfl_xor(s, off);
  const float mean = s * (1.f / 512.f);
  float sq = 0.f;
#pragma unroll
  for (int j = 0; j < 8; j++) { v[j] -= mean; sq += v[j] * v[j]; }
#pragma unroll
  for (int off = 1; off < 64; off <<= 1) sq += __shfl_xor(sq, off);
  const float inv = rsqrtf(sq * (1.f / 512.f) + 1e-6f);
  bf16x8_t hv, lv;
#pragma unroll
  for (int j = 0; j < 8; j++) {
    const float o = v[j] * inv * g[lane * 8 + j] + bb[lane * 8 + j];
    const __bf16 h = (__bf16)o;
    hv[j] = h; lv[j] = (__bf16)(o - (float)h);
  }
  *reinterpret_cast<bf16x8_t*>(&yh[(size_t)row * 512 + lane * 8]) = hv;
  *reinterpret_cast<bf16x8_t*>(&yl[(size_t)row * 512 + lane * 8]) = lv;
}

// ---------------------------------------------------------------------------
// Split-bf16 MFMA GEMM v2 (m97 structure): all operands bf16 hi/lo planes,
// global_load_lds staging with XOR-swizzled global source, BK=64, 128x128
// tile, 4 waves. C[M,N] = (Ah+Al)(Bh+Bl) ~= AhBh + AhBl + AlBh.
// A sections: cols >= ksplit come from A1 planes (gate). B is [N][K].
// EPI: 0 f32  1 planes  2 planes+relu  3 gate  4 f32+residual
// Output addr: (col>>9)*sec_stride + row*ldc + (col&511)
// ---------------------------------------------------------------------------
template <int EPI>
__global__ __launch_bounds__(256, 2) void gemm2_kernel(
    const __bf16* __restrict__ A0h, const __bf16* __restrict__ A0l,
    const __bf16* __restrict__ A1h, const __bf16* __restrict__ A1l,
    int lda, int ksplit,
    const __bf16* __restrict__ Bh, const __bf16* __restrict__ Bl, int K,
    const float* __restrict__ bias,
    float* __restrict__ Cf, __bf16* __restrict__ Ch, __bf16* __restrict__ Cl,
    int ldc, size_t sec_stride,
    const __bf16* __restrict__ e0h, const __bf16* __restrict__ e0l,
    const __bf16* __restrict__ e1h, const __bf16* __restrict__ e1l,
    const float* __restrict__ e2) {
  __shared__ __bf16 lds[4][128][64];   // Ah, Al, Bh, Bl ; row = 128 B
  const int tid = threadIdx.x;
  const int wave = tid >> 6, lane = tid & 63;
  const int brow = blockIdx.y * 128, bcol = blockIdx.x * 128;
  const int wr = (wave >> 1) * 64, wc = (wave & 1) * 64;
  const int lr = lane & 15, hi = lane >> 4;
  // staging map: lane -> row_off 0..7, src chunk = (lane&7)^(row_off) (swizzle)
  const int s_row = lane >> 3;
  const int s_sc = (lane & 7) ^ s_row;
  const int tile_row = (wave < 2 ? brow : bcol) + s_row;

  f32x4_t acc[4][4] = {};

  for (int k0 = 0; k0 < K; k0 += 64) {
    const __bf16* ah = A0h; const __bf16* al = A0l; int kc = k0;
    if (k0 >= ksplit) { ah = A1h; al = A1l; kc = k0 - ksplit; }
    const __bf16* plane = wave == 0 ? ah : wave == 1 ? al : wave == 2 ? Bh : Bl;
    const int pl_lda = wave < 2 ? lda : K;
    const int pk = wave < 2 ? kc : k0;
    const __bf16* src = plane + (size_t)tile_row * pl_lda + pk + s_sc * 8;
#pragma unroll
    for (int i = 0; i < 16; i++)
      gload16(src + (size_t)i * 8 * pl_lda, &lds[wave][i * 8][0]);
    __syncthreads();   // drains vmcnt -> LDS tile ready
#pragma unroll
    for (int kk = 0; kk < 2; kk++) {
      bf16x8_t afh[4], afl[4], bfh[4], bfl[4];
#pragma unroll
      for (int m = 0; m < 4; m++) {
        const int row = wr + m * 16 + lr;
        const int ch = (kk * 4 + hi) ^ (row & 7);
        afh[m] = *(const bf16x8_t*)((const char*)&lds[0][0][0] + row * 128 + ch * 16);
        afl[m] = *(const bf16x8_t*)((const char*)&lds[1][0][0] + row * 128 + ch * 16);
      }
#pragma unroll
      for (int n = 0; n < 4; n++) {
        const int row = wc + n * 16 + lr;
        const int ch = (kk * 4 + hi) ^ (row & 7);
        bfh[n] = *(const bf16x8_t*)((const char*)&lds[2][0][0] + row * 128 + ch * 16);
        bfl[n] = *(const bf16x8_t*)((const char*)&lds[3][0][0] + row * 128 + ch * 16);
      }
#pragma unroll
      for (int m = 0; m < 4; m++)
#pragma unroll
        for (int n = 0; n < 4; n++) {
          acc[m][n] = __builtin_amdgcn_mfma_f32_16x16x32_bf16(afh[m], bfh[n], acc[m][n], 0, 0, 0);
          acc[m][n] = __builtin_amdgcn_mfma_f32_16x16x32_bf16(afh[m], bfl[n], acc[m][n], 0, 0, 0);
          acc[m][n] = __builtin_amdgcn_mfma_f32_16x16x32_bf16(afl[m], bfh[n], acc[m][n], 0, 0, 0);
        }
    }
    __syncthreads();   // everyone done reading before next stage overwrites
  }

#pragma unroll
  for (int m = 0; m < 4; m++) {
#pragma unroll
    for (int n = 0; n < 4; n++) {
      const int colg = bcol + wc + n * 16 + lr;
      const size_t cb = (size_t)(colg >> 9) * sec_stride + (colg & 511);
      const float bv = bias[colg];
#pragma unroll
      for (int r = 0; r < 4; r++) {
        const int row = brow + wr + m * 16 + hi * 4 + r;
        float v = acc[m][n][r] + bv;
        if constexpr (EPI == 0) {
          Cf[cb + (size_t)row * ldc] = v;
        } else if constexpr (EPI == 1) {
          const __bf16 h = (__bf16)v;
          Ch[cb + (size_t)row * ldc] = h;
          Cl[cb + (size_t)row * ldc] = (__bf16)(v - (float)h);
        } else if constexpr (EPI == 2) {
          v = fmaxf(v, 0.f);
          const __bf16 h = (__bf16)v;
          Ch[cb + (size_t)row * ldc] = h;
          Cl[cb + (size_t)row * ldc] = (__bf16)(v - (float)h);
        } else if constexpr (EPI == 3) {
          const float z = 1.f / (1.f + expf(-v));
          const size_t ei = (size_t)row * 512 + colg;
          const float a = (float)e0h[ei] + (float)e0l[ei];
          const float c = (float)e1h[ei] + (float)e1l[ei];
          Cf[cb + (size_t)row * ldc] = z * a + (1.f - z) * c + e2[ei];
        } else if constexpr (EPI == 4) {
          Cf[cb + (size_t)row * ldc] = v + e2[(size_t)row * 512 + colg];
        }
      }
    }
  }
}

// ---------------------------------------------------------------------------
// Self-attention, flash-style. Block = (b, h, 64-row q tile). Emits planes.
// ---------------------------------------------------------------------------
__global__ __launch_bounds__(256) void sa_attn_kernel(
    const float* __restrict__ Q, const float* __restrict__ K,
    const float* __restrict__ V, const int* __restrict__ mask,
    __bf16* __restrict__ Oh, __bf16* __restrict__ Ol) {
  __shared__ float qs[64][67];
  __shared__ float ks[64][67];
  __shared__ float vs[64][67];
  const int tid = threadIdx.x;
  const int b = blockIdx.z, h = blockIdx.y, q0 = blockIdx.x * 64;
  const int ty = tid >> 4, tx = tid & 15;
#pragma unroll
  for (int i = 0; i < 4; i++) {
    const int fi = i * 256 + tid;
    const int r = fi >> 4, dq = (fi & 15) << 2;
    const float4 v = *reinterpret_cast<const float4*>(&Q[((size_t)(b * 512 + q0 + r)) * 512 + h * 64 + dq]);
    qs[r][dq] = v.x; qs[r][dq + 1] = v.y; qs[r][dq + 2] = v.z; qs[r][dq + 3] = v.w;
  }
  float m[4], l[4], o[4][4];
#pragma unroll
  for (int i = 0; i < 4; i++) {
    m[i] = -INFINITY; l[i] = 0.f;
#pragma unroll
    for (int j = 0; j < 4; j++) o[i][j] = 0.f;
  }
  for (int kt = 0; kt < 8; kt++) {
    const int k0 = kt * 64;
    __syncthreads();
#pragma unroll
    for (int i = 0; i < 4; i++) {
      const int fi = i * 256 + tid;
      const int r = fi >> 4, dq = (fi & 15) << 2;
      const float4 kv = *reinterpret_cast<const float4*>(&K[((size_t)(b * 512 + k0 + r)) * 512 + h * 64 + dq]);
      ks[r][dq] = kv.x; ks[r][dq + 1] = kv.y; ks[r][dq + 2] = kv.z; ks[r][dq + 3] = kv.w;
      const float4 vv = *reinterpret_cast<const float4*>(&V[((size_t)(b * 512 + k0 + r)) * 512 + h * 64 + dq]);
      vs[r][dq] = vv.x; vs[r][dq + 1] = vv.y; vs[r][dq + 2] = vv.z; vs[r][dq + 3] = vv.w;
    }
    __syncthreads();
    float s[4][4] = {};
#pragma unroll 8
    for (int d = 0; d < 64; d++) {
      float qv[4], kv[4];
#pragma unroll
      for (int i = 0; i < 4; i++) qv[i] = qs[ty * 4 + i][d];
#pragma unroll
      for (int j = 0; j < 4; j++) kv[j] = ks[tx * 4 + j][d];
#pragma unroll
      for (int i = 0; i < 4; i++)
#pragma unroll
        for (int j = 0; j < 4; j++) s[i][j] += qv[i] * kv[j];
    }
    float scale[4];
#pragma unroll
    for (int i = 0; i < 4; i++) {
      const int qi = q0 + ty * 4 + i;
      const int4 mv = *reinterpret_cast<const int4*>(&mask[((size_t)b * 512 + qi) * 512 + k0 + tx * 4]);
      s[i][0] = mv.x ? -1e18f : s[i][0] * 0.125f;
      s[i][1] = mv.y ? -1e18f : s[i][1] * 0.125f;
      s[i][2] = mv.z ? -1e18f : s[i][2] * 0.125f;
      s[i][3] = mv.w ? -1e18f : s[i][3] * 0.125f;
      float mx = fmaxf(fmaxf(s[i][0], s[i][1]), fmaxf(s[i][2], s[i][3]));
#pragma unroll
      for (int off = 1; off <= 8; off <<= 1) mx = fmaxf(mx, __shfl_xor(mx, off));
      const float mnew = fmaxf(m[i], mx);
      float rs = 0.f;
#pragma unroll
      for (int j = 0; j < 4; j++) { const float p = expf(s[i][j] - mnew); s[i][j] = p; rs += p; }
#pragma unroll
      for (int off = 1; off <= 8; off <<= 1) rs += __shfl_xor(rs, off);
      scale[i] = expf(m[i] - mnew);
      l[i] = l[i] * scale[i] + rs;
      m[i] = mnew;
    }
    __syncthreads();
#pragma unroll
    for (int i = 0; i < 4; i++)
#pragma unroll
      for (int j = 0; j < 4; j++) ks[ty * 4 + i][tx * 4 + j] = s[i][j];
#pragma unroll
    for (int i = 0; i < 4; i++)
#pragma unroll
      for (int j = 0; j < 4; j++) o[i][j] *= scale[i];
    __syncthreads();
#pragma unroll 8
    for (int kk = 0; kk < 64; kk++) {
      float pv[4], vv[4];
#pragma unroll
      for (int i = 0; i < 4; i++) pv[i] = ks[ty * 4 + i][kk];
#pragma unroll
      for (int j = 0; j < 4; j++) vv[j] = vs[kk][tx * 4 + j];
#pragma unroll
      for (int i = 0; i < 4; i++)
#pragma unroll
        for (int j = 0; j < 4; j++) o[i][j] += pv[i] * vv[j];
    }
  }
#pragma unroll
  for (int i = 0; i < 4; i++) {
    const float inv = 1.f / l[i];
    const size_t base = ((size_t)(b * 512 + q0 + ty * 4 + i)) * 512 + h * 64 + tx * 4;
    bf16x4_t hv, lv;
#pragma unroll
    for (int j = 0; j < 4; j++) {
      const float ov = o[i][j] * inv;
      const __bf16 hh = (__bf16)ov;
      hv[j] = hh; lv[j] = (__bf16)(ov - (float)hh);
    }
    *reinterpret_cast<bf16x4_t*>(&Oh[base]) = hv;
    *reinterpret_cast<bf16x4_t*>(&Ol[base]) = lv;
  }
}

// ---------------------------------------------------------------------------
// Cross-attention for a 16-chain chunk, emits ctxA planes.
// ---------------------------------------------------------------------------
__global__ __launch_bounds__(256) void ca_attn_kernel(
    const float* __restrict__ Qbase, const float* __restrict__ Kc,
    const float* __restrict__ Vc, const int* __restrict__ chain_map,
    const int* __restrict__ chain_mask,
    __bf16* __restrict__ Oh, __bf16* __restrict__ Ol, int c0) {
  __shared__ float ks[12][512];
  __shared__ float vs[12][512];
  const int tid = threadIdx.x;
  const int cl = blockIdx.y, c = c0 + cl, s0 = blockIdx.x * 32;
#pragma unroll
  for (int i = 0; i < 6; i++) {
    const int fi = i * 256 + tid;
    const int lrow = fi >> 7, dq = (fi & 127) << 2;
    *reinterpret_cast<float4*>(&ks[lrow][dq]) =
        *reinterpret_cast<const float4*>(&Kc[((size_t)c * 12 + lrow) * 512 + dq]);
    *reinterpret_cast<float4*>(&vs[lrow][dq]) =
        *reinterpret_cast<const float4*>(&Vc[((size_t)c * 12 + lrow) * 512 + dq]);
  }
  __syncthreads();
  const int h = tid >> 5, sl = tid & 31;
  const int s = s0 + sl;
  const int bq = chain_map[c];
  const float* qrow = &Qbase[((size_t)(bq * 512 + s)) * 512 + h * 64];
  float4 q4[16];
#pragma unroll
  for (int i = 0; i < 16; i++) q4[i] = *reinterpret_cast<const float4*>(&qrow[i * 4]);
  const int* mrow = &chain_mask[((size_t)(c * 512 + s)) * 12];
  float sc[12];
  float mx = -INFINITY;
#pragma unroll
  for (int lI = 0; lI < 12; lI++) {
    float acc = 0.f;
#pragma unroll
    for (int i = 0; i < 16; i++) {
      const float4 kv = *reinterpret_cast<const float4*>(&ks[lI][h * 64 + i * 4]);
      acc += q4[i].x * kv.x + q4[i].y * kv.y + q4[i].z * kv.z + q4[i].w * kv.w;
    }
    acc *= 0.125f;
    if (mrow[lI]) acc = -1e18f;
    sc[lI] = acc;
    mx = fmaxf(mx, acc);
  }
  float sum = 0.f;
#pragma unroll
  for (int lI = 0; lI < 12; lI++) { sc[lI] = expf(sc[lI] - mx); sum += sc[lI]; }
  const float inv = 1.f / sum;
  const size_t obase = ((size_t)(cl * 512 + s)) * 512 + h * 64;
#pragma unroll
  for (int dq = 0; dq < 16; dq++) {
    float4 ov = make_float4(0.f, 0.f, 0.f, 0.f);
#pragma unroll
    for (int lI = 0; lI < 12; lI++) {
      const float4 vv = *reinterpret_cast<const float4*>(&vs[lI][h * 64 + dq * 4]);
      ov.x += sc[lI] * vv.x; ov.y += sc[lI] * vv.y;
      ov.z += sc[lI] * vv.z; ov.w += sc[lI] * vv.w;
    }
    float vo[4] = {ov.x * inv, ov.y * inv, ov.z * inv, ov.w * inv};
    bf16x4_t hv, lv;
#pragma unroll
    for (int j = 0; j < 4; j++) {
      const __bf16 hh = (__bf16)vo[j];
      hv[j] = hh; lv[j] = (__bf16)(vo[j] - (float)hh);
    }
    *reinterpret_cast<bf16x4_t*>(&Oh[obase + dq * 4]) = hv;
    *reinterpret_cast<bf16x4_t*>(&Ol[obase + dq * 4]) = lv;
  }
}

// ---------------------------------------------------------------------------
// Running segment-max over a 16-chain chunk, planes in/out.
// MODE: 0 first, 1 mid, 2 last. Sentinel -3e38 (avoids inf-split NaN).
// ---------------------------------------------------------------------------
template <int MODE>
__global__ __launch_bounds__(256) void agg2_kernel(
    const float* __restrict__ ctxB, const int* __restrict__ chain_map,
    const int* __restrict__ chain_mask,
    __bf16* __restrict__ ch, __bf16* __restrict__ cl, int c0) {
  const int s = blockIdx.x, b = blockIdx.y, tid = threadIdx.x;
  const size_t orow = ((size_t)(b * 512 + s)) * 512;
  float v0 = -3.0e38f, v1 = -3.0e38f;
  if (MODE != 0) {
    v0 = (float)ch[orow + tid] + (float)cl[orow + tid];
    v1 = (float)ch[orow + 256 + tid] + (float)cl[orow + 256 + tid];
  }
  for (int i = 0; i < 16; i++) {
    const int c = c0 + i;
    if (chain_map[c] == b && chain_mask[((size_t)(c * 512 + s)) * 12] != 0) {
      const float* row = &ctxB[((size_t)(i * 512 + s)) * 512];
      v0 = fmaxf(v0, row[tid]);
      v1 = fmaxf(v1, row[tid + 256]);
    }
  }
  if (MODE == 2) {
    if (v0 < -1.0e38f) v0 = 0.f;
    if (v1 < -1.0e38f) v1 = 0.f;
  }
  const __bf16 h0 = (__bf16)v0, h1 = (__bf16)v1;
  ch[orow + tid] = h0;        cl[orow + tid] = (__bf16)(v0 - (float)h0);
  ch[orow + 256 + tid] = h1;  cl[orow + 256 + tid] = (__bf16)(v1 - (float)h1);
}

// ---------------------------------------------------------------------------
// Host launch
// ---------------------------------------------------------------------------
extern "C" void kernel_launch(void* const* d_in, const int* in_sizes, int n_in,
                              void* d_out, int out_size, void* d_ws, size_t ws_size,
                              hipStream_t stream) {
  const float* inputs     = (const float*)d_in[0];
  const int*   attn_mask  = (const int*)d_in[1];
  const int*   chain_map  = (const int*)d_in[2];
  const float* span       = (const float*)d_in[3];
  const int*   chain_mask = (const int*)d_in[4];
  const float* ln_g = (const float*)d_in[5];
  const float* ln_b = (const float*)d_in[6];
  const float* sa_bq = (const float*)d_in[8];
  const float* sa_bk = (const float*)d_in[10];
  const float* sa_bv = (const float*)d_in[12];
  const float* sa_bo = (const float*)d_in[14];
  const float* lc_b  = (const float*)d_in[16];
  const float* ca_bq = (const float*)d_in[18];
  const float* ca_bk = (const float*)d_in[20];
  const float* ca_bv = (const float*)d_in[22];
  const float* ca_bo = (const float*)d_in[24];
  const float* g_b   = (const float*)d_in[26];
  const float* ff_ln_g = (const float*)d_in[27];
  const float* ff_ln_b = (const float*)d_in[28];
  const float* ff_b1 = (const float*)d_in[30];
  const float* ff_b2 = (const float*)d_in[32];

  char* ws = (char*)d_ws;
  size_t off = 0;
  auto alloc = [&](size_t bytes) -> void* {
    off = (off + 255) & ~(size_t)255;
    void* p = ws + off;
    off += bytes;
    return p;
  };

  // --- weight planes: 9 pairs (qkv+caq fused into one [2048][512]) ---------
  // pair idx: 0 qkvq, 1 lc, 2 cak, 3 cav, 4 sao, 5 cao, 6 g, 7 f1, 8 f2
  const size_t wel[9] = {2048ull*512, 768ull*512, 512ull*512, 512ull*512,
                         512ull*512, 512ull*512, 1024ull*512, 512ull*2048, 2048ull*512};
  __bf16* WH[9]; __bf16* WL[9];
  for (int i = 0; i < 9; i++) {
    WH[i] = (__bf16*)alloc(wel[i] * 2);
    WL[i] = (__bf16*)alloc(wel[i] * 2);
  }
  WPack pack;
  // 12 descs: qkvq sections share pair 0 at N-offsets
  pack.w[0] = {(const float*)d_in[7],  WH[0],               WL[0],               512, 512};
  pack.w[1] = {(const float*)d_in[9],  WH[0] + 512*512,     WL[0] + 512*512,     512, 512};
  pack.w[2] = {(const float*)d_in[11], WH[0] + 1024*512,    WL[0] + 1024*512,    512, 512};
  pack.w[3] = {(const float*)d_in[17], WH[0] + 1536*512,    WL[0] + 1536*512,    512, 512};
  pack.w[4] = {(const float*)d_in[15], WH[1], WL[1], 768, 512};   // lc_w
  pack.w[5] = {(const float*)d_in[19], WH[2], WL[2], 512, 512};   // ca_wk
  pack.w[6] = {(const float*)d_in[21], WH[3], WL[3], 512, 512};   // ca_wv
  pack.w[7] = {(const float*)d_in[13], WH[4], WL[4], 512, 512};   // sa_wo
  pack.w[8] = {(const float*)d_in[23], WH[5], WL[5], 512, 512};   // ca_wo
  pack.w[9] = {(const float*)d_in[25], WH[6], WL[6], 1024, 512};  // g_w
  pack.w[10] = {(const float*)d_in[29], WH[7], WL[7], 512, 2048}; // ff_w1
  pack.w[11] = {(const float*)d_in[31], WH[8], WL[8], 2048, 512}; // ff_w2

  float* bias_cat = (float*)alloc(2048 * 4);

  // --- regions -------------------------------------------------------------
  const size_t E_BSD = 8192ull * 512;               // elements in a [8192,512]
  char* R_A = (char*)alloc(E_BSD * 4);              // 16.78 MB
  char* R_B = (char*)alloc(E_BSD * 16);             // 67.11 MB = 4 parts
  __bf16* spanh = (__bf16*)alloc(1536ull * 768 * 2);
  __bf16* spanl = (__bf16*)alloc(1536ull * 768 * 2);
  __bf16* embh  = (__bf16*)alloc(1536ull * 512 * 2);
  __bf16* embl  = (__bf16*)alloc(1536ull * 512 * 2);
  float*  v_ca  = (float*)alloc(1536ull * 512 * 4);
  if (ws_size < off) return;   // fail visibly, not fault

  // R_A: x_norm planes -> sa_ctx planes -> ctxA planes -> out1 f32
  __bf16* xh = (__bf16*)R_A;           __bf16* xl = xh + E_BSD;
  __bf16* sh = xh;                     __bf16* sl = xl;      // sa_ctx
  __bf16* cah = xh;                    __bf16* cal = xl;     // ctxA
  float*  out1 = (float*)R_A;
  // R_B parts (16.78 MB each)
  float* QKVQ = (float*)R_B;                      // fused proj output (4 sections)
  float* saQ = QKVQ;
  float* saK = QKVQ + E_BSD;
  float* saV = QKVQ + 2 * E_BSD;
  float* caQ = QKVQ + 3 * E_BSD;
  float*  ctxB  = (float*)R_B;                    // part 0 (after sa_attn)
  __bf16* ah_pl = (__bf16*)(R_B + E_BSD * 4);     // part 1: attn planes
  __bf16* al_pl = ah_pl + E_BSD;
  __bf16* cth   = (__bf16*)(R_B + E_BSD * 8);     // part 2: ctx planes
  __bf16* ctl   = cth + E_BSD;
  __bf16* yh    = (__bf16*)(R_B + E_BSD * 12);    // part 3: y planes
  __bf16* yl    = yh + E_BSD;
  __bf16* ih    = (__bf16*)R_B;                   // inter planes (parts 0+1)
  __bf16* il    = ih + 4096ull * 2048;
  float* k_ca = (float*)spanh;                    // span dead after lc gemm
  float* dout = (float*)d_out;
  const int KBIG = 1 << 30;
  const float* Z = nullptr;
  const __bf16* ZB = nullptr;

  auto gemm = [&](int EPI, const __bf16* a0h, const __bf16* a0l,
                  const __bf16* a1h, const __bf16* a1l, int lda, int ksplit,
                  int wi, int K, const float* bias,
                  float* cf, __bf16* chp, __bf16* clp, int ldc, size_t secs,
                  const __bf16* E0h, const __bf16* E0l,
                  const __bf16* E1h, const __bf16* E1l, const float* E2,
                  int M, int N) {
    dim3 grid(N / 128, M / 128);
    switch (EPI) {
      case 0: gemm2_kernel<0><<<grid, 256, 0, stream>>>(a0h, a0l, a1h, a1l, lda, ksplit, WH[wi], WL[wi], K, bias, cf, chp, clp, ldc, secs, E0h, E0l, E1h, E1l, E2); break;
      case 1: gemm2_kernel<1><<<grid, 256, 0, stream>>>(a0h, a0l, a1h, a1l, lda, ksplit, WH[wi], WL[wi], K, bias, cf, chp, clp, ldc, secs, E0h, E0l, E1h, E1l, E2); break;
      case 2: gemm2_kernel<2><<<grid, 256, 0, stream>>>(a0h, a0l, a1h, a1l, lda, ksplit, WH[wi], WL[wi], K, bias, cf, chp, clp, ldc, secs, E0h, E0l, E1h, E1l, E2); break;
      case 3: gemm2_kernel<3><<<grid, 256, 0, stream>>>(a0h, a0l, a1h, a1l, lda, ksplit, WH[wi], WL[wi], K, bias, cf, chp, clp, ldc, secs, E0h, E0l, E1h, E1l, E2); break;
      case 4: gemm2_kernel<4><<<grid, 256, 0, stream>>>(a0h, a0l, a1h, a1l, lda, ksplit, WH[wi], WL[wi], K, bias, cf, chp, clp, ldc, secs, E0h, E0l, E1h, E1l, E2); break;
    }
  };

  prep_weights_kernel<<<dim3(64, 12), 256, 0, stream>>>(pack);
  bias_cat_kernel<<<8, 256, 0, stream>>>(sa_bq, sa_bk, sa_bv, ca_bq, bias_cat);
  split_kernel<<<1152, 256, 0, stream>>>(span, spanh, spanl, 1536 * 768 / 4);
  ln_split_kernel<<<2048, 256, 0, stream>>>(inputs, ln_g, ln_b, xh, xl);

  // fused QKV + CA-Q projection: [8192,2048], sections -> 4 contiguous bufs
  gemm(0, xh, xl, xh, xl, 512, KBIG, 0, 512, bias_cat,
       QKVQ, nullptr, nullptr, 512, (size_t)E_BSD,
       ZB, ZB, ZB, ZB, Z, 8192, 2048);

  sa_attn_kernel<<<dim3(8, 8, 16), 256, 0, stream>>>(saQ, saK, saV, attn_mask, sh, sl);
  // sa_wo -> attn planes (part 1; saK dead)
  gemm(1, sh, sl, sh, sl, 512, KBIG, 4, 512, sa_bo,
       nullptr, ah_pl, al_pl, 512, 0, ZB, ZB, ZB, ZB, Z, 8192, 512);

  // cross-attention K/V precompute
  gemm(1, spanh, spanl, spanh, spanl, 768, KBIG, 1, 768, lc_b,
       nullptr, embh, embl, 512, 0, ZB, ZB, ZB, ZB, Z, 1536, 512);
  gemm(0, embh, embl, embh, embl, 512, KBIG, 2, 512, ca_bk,
       k_ca, nullptr, nullptr, 512, 0, ZB, ZB, ZB, ZB, Z, 1536, 512);
  gemm(0, embh, embl, embh, embl, 512, KBIG, 3, 512, ca_bv,
       v_ca, nullptr, nullptr, 512, 0, ZB, ZB, ZB, ZB, Z, 1536, 512);

  // CA in 8 chunks of 16 chains; running segment-max into ctx planes
  for (int chk = 0; chk < 8; chk++) {
    const int c0 = chk * 16;
    ca_attn_kernel<<<dim3(16, 16), 256, 0, stream>>>(caQ, k_ca, v_ca, chain_map, chain_mask, cah, cal, c0);
    gemm(0, cah, cal, cah, cal, 512, KBIG, 5, 512, ca_bo,
         ctxB, nullptr, nullptr, 512, 0, ZB, ZB, ZB, ZB, Z, 8192, 512);
    if (chk == 0)      agg2_kernel<0><<<dim3(512, 16), 256, 0, stream>>>(ctxB, chain_map, chain_mask, cth, ctl, c0);
    else if (chk == 7) agg2_kernel<2><<<dim3(512, 16), 256, 0, stream>>>(ctxB, chain_map, chain_mask, cth, ctl, c0);
    else               agg2_kernel<1><<<dim3(512, 16), 256, 0, stream>>>(ctxB, chain_map, chain_mask, cth, ctl, c0);
  }

  // gate: A = [attn planes | ctx planes], epilogue z*a+(1-z)*c+inputs -> out1
  gemm(3, ah_pl, al_pl, cth, ctl, 512, 512, 6, 1024, g_b,
       out1, nullptr, nullptr, 512, 0, ah_pl, al_pl, cth, ctl, inputs, 8192, 512);

  // feed-forward
  ln_split_kernel<<<2048, 256, 0, stream>>>(out1, ff_ln_g, ff_ln_b, yh, yl);
  for (int r0 = 0; r0 < 8192; r0 += 4096) {
    gemm(2, yh + (size_t)r0 * 512, yl + (size_t)r0 * 512,
         yh + (size_t)r0 * 512, yl + (size_t)r0 * 512, 512, KBIG, 7, 512, ff_b1,
         nullptr, ih, il, 2048, 512, ZB, ZB, ZB, ZB, Z, 4096, 2048);
    gemm(4, ih, il, ih, il, 2048, KBIG, 8, 2048, ff_b2,
         dout + (size_t)r0 * 512, nullptr, nullptr, 512, 0,
         ZB, ZB, ZB, ZB, out1 + (size_t)r0 * 512, 4096, 512);
  }
}

// Round 6
// 1195.735 us; speedup vs baseline: 1.9346x; 1.0006x over previous
//
#include <hip/hip_runtime.h>
#include <hip/hip_bf16.h>
#include <math.h>

typedef float f32x4_t __attribute__((ext_vector_type(4)));
typedef __bf16 bf16x8_t __attribute__((ext_vector_type(8)));
typedef __bf16 bf16x4_t __attribute__((ext_vector_type(4)));

__device__ __forceinline__ void gload16(const void* g, void* l) {
  __builtin_amdgcn_global_load_lds((const __attribute__((address_space(1))) void*)g,
                                   (__attribute__((address_space(3))) void*)l, 16, 0, 0);
}

// ---------------------------------------------------------------------------
// Weight prep: fp32 W[K][N] -> bf16 hi/lo planes, transposed to [N][K].
// ---------------------------------------------------------------------------
struct WDesc { const float* src; __bf16* hi; __bf16* lo; int K; int N; };
struct WPack { WDesc w[12]; };

__global__ __launch_bounds__(256) void prep_weights_kernel(WPack p) {
  WDesc d = p.w[blockIdx.y];
  const int tilesN = d.N >> 6;
  const int ntiles = (d.K >> 6) * tilesN;
  __shared__ float tile[64][65];
  const int tid = threadIdx.x;
  const int r = tid >> 4, cq = (tid & 15) << 2;
  const int c = tid >> 4, rq = (tid & 15) << 2;
  for (int t = blockIdx.x; t < ntiles; t += gridDim.x) {
    const int tk = t / tilesN, tn = t - tk * tilesN;
    const int k0 = tk << 6, n0 = tn << 6;
#pragma unroll
    for (int i = 0; i < 4; i++) {
      const float4 v = *reinterpret_cast<const float4*>(
          &d.src[(size_t)(k0 + r + i * 16) * d.N + n0 + cq]);
      tile[r + i * 16][cq] = v.x; tile[r + i * 16][cq + 1] = v.y;
      tile[r + i * 16][cq + 2] = v.z; tile[r + i * 16][cq + 3] = v.w;
    }
    __syncthreads();
#pragma unroll
    for (int i = 0; i < 4; i++) {
      const int cc = c + i * 16;
      const float v0 = tile[rq][cc], v1 = tile[rq + 1][cc];
      const float v2 = tile[rq + 2][cc], v3 = tile[rq + 3][cc];
      const __bf16 h0 = (__bf16)v0, h1 = (__bf16)v1, h2 = (__bf16)v2, h3 = (__bf16)v3;
      bf16x4_t hv = {h0, h1, h2, h3};
      bf16x4_t lv = {(__bf16)(v0 - (float)h0), (__bf16)(v1 - (float)h1),
                     (__bf16)(v2 - (float)h2), (__bf16)(v3 - (float)h3)};
      *reinterpret_cast<bf16x4_t*>(&d.hi[(size_t)(n0 + cc) * d.K + k0 + rq]) = hv;
      *reinterpret_cast<bf16x4_t*>(&d.lo[(size_t)(n0 + cc) * d.K + k0 + rq]) = lv;
    }
    __syncthreads();
  }
}

__global__ __launch_bounds__(256) void bias_cat_kernel(
    const float* __restrict__ b0, const float* __restrict__ b1,
    const float* __restrict__ b2, const float* __restrict__ b3,
    float* __restrict__ out) {
  const int t = blockIdx.x * 256 + threadIdx.x;   // grid 8 -> 2048
  const float* s = t < 512 ? b0 : t < 1024 ? b1 : t < 1536 ? b2 : b3;
  out[t] = s[t & 511];
}

// fp32 -> hi/lo bf16 planes (for span_embeddings)
__global__ __launch_bounds__(256) void split_kernel(
    const float* __restrict__ x, __bf16* __restrict__ h, __bf16* __restrict__ l, int nq) {
  const int i = blockIdx.x * 256 + threadIdx.x;
  if (i >= nq) return;
  const float4 v = reinterpret_cast<const float4*>(x)[i];
  const __bf16 h0 = (__bf16)v.x, h1 = (__bf16)v.y, h2 = (__bf16)v.z, h3 = (__bf16)v.w;
  bf16x4_t hv = {h0, h1, h2, h3};
  bf16x4_t lv = {(__bf16)(v.x - (float)h0), (__bf16)(v.y - (float)h1),
                 (__bf16)(v.z - (float)h2), (__bf16)(v.w - (float)h3)};
  reinterpret_cast<bf16x4_t*>(h)[i] = hv;
  reinterpret_cast<bf16x4_t*>(l)[i] = lv;
}

// ---------------------------------------------------------------------------
// LayerNorm over D=512, one wave per row, emits hi/lo bf16 planes
// ---------------------------------------------------------------------------
__global__ __launch_bounds__(256) void ln_split_kernel(
    const float* __restrict__ x, const float* __restrict__ g,
    const float* __restrict__ bb, __bf16* __restrict__ yh, __bf16* __restrict__ yl) {
  const int row = blockIdx.x * 4 + (threadIdx.x >> 6);
  const int lane = threadIdx.x & 63;
  const float* xr = x + (size_t)row * 512;
  float4 a = *reinterpret_cast<const float4*>(&xr[lane * 8]);
  float4 b4 = *reinterpret_cast<const float4*>(&xr[lane * 8 + 4]);
  float v[8] = {a.x, a.y, a.z, a.w, b4.x, b4.y, b4.z, b4.w};
  float s = 0.f;
#pragma unroll
  for (int j = 0; j < 8; j++) s += v[j];
#pragma unroll
  for (int off = 1; off < 64; off <<= 1) s += __shfl_xor(s, off);
  const float mean = s * (1.f / 512.f);
  float sq = 0.f;
#pragma unroll
  for (int j = 0; j < 8; j++) { v[j] -= mean; sq += v[j] * v[j]; }
#pragma unroll
  for (int off = 1; off < 64; off <<= 1) sq += __shfl_xor(sq, off);
  const float inv = rsqrtf(sq * (1.f / 512.f) + 1e-6f);
  bf16x8_t hv, lv;
#pragma unroll
  for (int j = 0; j < 8; j++) {
    const float o = v[j] * inv * g[lane * 8 + j] + bb[lane * 8 + j];
    const __bf16 h = (__bf16)o;
    hv[j] = h; lv[j] = (__bf16)(o - (float)h);
  }
  *reinterpret_cast<bf16x8_t*>(&yh[(size_t)row * 512 + lane * 8]) = hv;
  *reinterpret_cast<bf16x8_t*>(&yl[(size_t)row * 512 + lane * 8]) = lv;
}

// ---------------------------------------------------------------------------
// Split-bf16 MFMA GEMM v2: operands bf16 hi/lo planes, global_load_lds with
// XOR-swizzled global source, BK=64, 128x128 tile, 4 waves.
// EPI: 0 f32  1 planes  2 planes+relu  3 gate  4 f32+residual
//      5 qkvq special: sec0->Ch/Cl (Q planes), sec1->C2h/C2l (K planes),
//        sec2->C3h/C3l (V transposed planes [b][h][dv][s]), sec3->Cf f32.
// ---------------------------------------------------------------------------
template <int EPI>
__global__ __launch_bounds__(256, 2) void gemm2_kernel(
    const __bf16* __restrict__ A0h, const __bf16* __restrict__ A0l,
    const __bf16* __restrict__ A1h, const __bf16* __restrict__ A1l,
    int lda, int ksplit,
    const __bf16* __restrict__ Bh, const __bf16* __restrict__ Bl, int K,
    const float* __restrict__ bias,
    float* __restrict__ Cf, __bf16* __restrict__ Ch, __bf16* __restrict__ Cl,
    __bf16* __restrict__ C2h, __bf16* __restrict__ C2l,
    __bf16* __restrict__ C3h, __bf16* __restrict__ C3l,
    int ldc, size_t sec_stride,
    const __bf16* __restrict__ e0h, const __bf16* __restrict__ e0l,
    const __bf16* __restrict__ e1h, const __bf16* __restrict__ e1l,
    const float* __restrict__ e2) {
  __shared__ __bf16 lds[4][128][64];   // Ah, Al, Bh, Bl
  const int tid = threadIdx.x;
  const int wave = tid >> 6, lane = tid & 63;
  const int brow = blockIdx.y * 128, bcol = blockIdx.x * 128;
  const int wr = (wave >> 1) * 64, wc = (wave & 1) * 64;
  const int lr = lane & 15, hi = lane >> 4;
  const int s_row = lane >> 3;
  const int s_sc = (lane & 7) ^ s_row;
  const int tile_row = (wave < 2 ? brow : bcol) + s_row;

  f32x4_t acc[4][4] = {};

  for (int k0 = 0; k0 < K; k0 += 64) {
    const __bf16* ah = A0h; const __bf16* al = A0l; int kc = k0;
    if (k0 >= ksplit) { ah = A1h; al = A1l; kc = k0 - ksplit; }
    const __bf16* plane = wave == 0 ? ah : wave == 1 ? al : wave == 2 ? Bh : Bl;
    const int pl_lda = wave < 2 ? lda : K;
    const int pk = wave < 2 ? kc : k0;
    const __bf16* src = plane + (size_t)tile_row * pl_lda + pk + s_sc * 8;
#pragma unroll
    for (int i = 0; i < 16; i++)
      gload16(src + (size_t)i * 8 * pl_lda, &lds[wave][i * 8][0]);
    __syncthreads();
#pragma unroll
    for (int kk = 0; kk < 2; kk++) {
      bf16x8_t afh[4], afl[4], bfh[4], bfl[4];
#pragma unroll
      for (int m = 0; m < 4; m++) {
        const int row = wr + m * 16 + lr;
        const int ch = (kk * 4 + hi) ^ (row & 7);
        afh[m] = *(const bf16x8_t*)((const char*)&lds[0][0][0] + row * 128 + ch * 16);
        afl[m] = *(const bf16x8_t*)((const char*)&lds[1][0][0] + row * 128 + ch * 16);
      }
#pragma unroll
      for (int n = 0; n < 4; n++) {
        const int row = wc + n * 16 + lr;
        const int ch = (kk * 4 + hi) ^ (row & 7);
        bfh[n] = *(const bf16x8_t*)((const char*)&lds[2][0][0] + row * 128 + ch * 16);
        bfl[n] = *(const bf16x8_t*)((const char*)&lds[3][0][0] + row * 128 + ch * 16);
      }
#pragma unroll
      for (int m = 0; m < 4; m++)
#pragma unroll
        for (int n = 0; n < 4; n++) {
          acc[m][n] = __builtin_amdgcn_mfma_f32_16x16x32_bf16(afh[m], bfh[n], acc[m][n], 0, 0, 0);
          acc[m][n] = __builtin_amdgcn_mfma_f32_16x16x32_bf16(afh[m], bfl[n], acc[m][n], 0, 0, 0);
          acc[m][n] = __builtin_amdgcn_mfma_f32_16x16x32_bf16(afl[m], bfh[n], acc[m][n], 0, 0, 0);
        }
    }
    __syncthreads();
  }

#pragma unroll
  for (int m = 0; m < 4; m++) {
#pragma unroll
    for (int n = 0; n < 4; n++) {
      const int colg = bcol + wc + n * 16 + lr;
      const size_t cb = (size_t)(colg >> 9) * sec_stride + (colg & 511);
      const float bv = bias[colg];
#pragma unroll
      for (int r = 0; r < 4; r++) {
        const int row = brow + wr + m * 16 + hi * 4 + r;
        float v = acc[m][n][r] + bv;
        if constexpr (EPI == 0) {
          Cf[cb + (size_t)row * ldc] = v;
        } else if constexpr (EPI == 1) {
          const __bf16 h = (__bf16)v;
          Ch[cb + (size_t)row * ldc] = h;
          Cl[cb + (size_t)row * ldc] = (__bf16)(v - (float)h);
        } else if constexpr (EPI == 2) {
          v = fmaxf(v, 0.f);
          const __bf16 h = (__bf16)v;
          Ch[cb + (size_t)row * ldc] = h;
          Cl[cb + (size_t)row * ldc] = (__bf16)(v - (float)h);
        } else if constexpr (EPI == 3) {
          const float z = 1.f / (1.f + expf(-v));
          const size_t ei = (size_t)row * 512 + colg;
          const float a = (float)e0h[ei] + (float)e0l[ei];
          const float c = (float)e1h[ei] + (float)e1l[ei];
          Cf[cb + (size_t)row * ldc] = z * a + (1.f - z) * c + e2[ei];
        } else if constexpr (EPI == 4) {
          Cf[cb + (size_t)row * ldc] = v + e2[(size_t)row * 512 + colg];
        } else if constexpr (EPI == 5) {
          const int sec = colg >> 9, cc = colg & 511;
          const __bf16 h = (__bf16)v;
          const __bf16 lo = (__bf16)(v - (float)h);
          if (sec == 0)      { Ch[(size_t)row * 512 + cc] = h;  Cl[(size_t)row * 512 + cc] = lo; }
          else if (sec == 1) { C2h[(size_t)row * 512 + cc] = h; C2l[(size_t)row * 512 + cc] = lo; }
          else if (sec == 2) {
            const int bb2 = row >> 9, ss = row & 511, hh2 = cc >> 6, dv = cc & 63;
            const size_t va = ((size_t)((bb2 * 8 + hh2) * 64 + dv)) * 512 + ss;
            C3h[va] = h; C3l[va] = lo;
          } else {
            Cf[(size_t)row * 512 + cc] = v;
          }
        }
      }
    }
  }
}

// ---------------------------------------------------------------------------
// MFMA flash self-attention. Block = (q-tile 64, h, b), 4 waves; each wave
// owns 16 q rows. Split-bf16 QK^T and PV (3 MFMAs each). V pre-transposed
// planes [b][h][dv][s]. LDS staged via gload16 + XOR swizzle (gemm2 scheme).
// ---------------------------------------------------------------------------
__global__ __launch_bounds__(256, 2) void sa_attn_mfma_kernel(
    const __bf16* __restrict__ Qh_g, const __bf16* __restrict__ Ql_g,
    const __bf16* __restrict__ Kh_g, const __bf16* __restrict__ Kl_g,
    const __bf16* __restrict__ Vth_g, const __bf16* __restrict__ Vtl_g,
    const int* __restrict__ mask,
    __bf16* __restrict__ Oh, __bf16* __restrict__ Ol) {
  __shared__ __bf16 Qs[2][64][64];
  __shared__ __bf16 Ks[2][64][64];
  __shared__ __bf16 Vs[2][64][64];   // transposed: [dv][k]
  __shared__ __bf16 Ps[2][64][64];   // P planes, wave-private rows
  const int tid = threadIdx.x;
  const int wid = tid >> 6, lane = tid & 63;
  const int q0 = blockIdx.x * 64;
  const int h = blockIdx.y, b = blockIdx.z;
  const int lr = lane & 15, hi = lane >> 4;
  const int s_row = lane >> 3;
  const int s_sc = (lane & 7) ^ s_row;

  // stage Q once: waves 0,1 -> Qh halves; waves 2,3 -> Ql halves
  {
    const __bf16* qp = (wid < 2 ? Qh_g : Ql_g);
    const int pl = (wid < 2 ? 0 : 1);
    const int r0 = (wid & 1) * 32;
    const __bf16* src = qp + (size_t)(b * 512 + q0 + r0 + s_row) * 512 + h * 64 + s_sc * 8;
#pragma unroll
    for (int i = 0; i < 4; i++)
      gload16(src + (size_t)i * 8 * 512, &Qs[pl][r0 + i * 8][0]);
  }
  f32x4_t accO[4] = {};
  float m_[4], l_[4];
#pragma unroll
  for (int j = 0; j < 4; j++) { m_[j] = -INFINITY; l_[j] = 0.f; }

  for (int kt = 0; kt < 8; kt++) {
    const int k0 = kt * 64;
    __syncthreads();   // previous tile's reads done before overwrite
    {
      const __bf16* plane = wid == 0 ? Kh_g : wid == 1 ? Kl_g : wid == 2 ? Vth_g : Vtl_g;
      size_t srow; int scol;
      if (wid < 2) { srow = (size_t)(b * 512 + k0 + s_row);          scol = h * 64; }
      else         { srow = (size_t)((b * 8 + h) * 64 + s_row);      scol = k0; }
      const __bf16* src = plane + srow * 512 + scol + s_sc * 8;
      __bf16* dst0 = (wid == 0) ? &Ks[0][0][0] : (wid == 1) ? &Ks[1][0][0]
                   : (wid == 2) ? &Vs[0][0][0] : &Vs[1][0][0];
#pragma unroll
      for (int i = 0; i < 8; i++)
        gload16(src + (size_t)i * 8 * 512, dst0 + i * 8 * 64);
    }
    __syncthreads();   // K/V tile ready (vmcnt drained by barrier)

    // ---- QK^T: S[16q x 64k] per wave, split 3x ----
    f32x4_t acc[4] = {};
#pragma unroll
    for (int kk = 0; kk < 2; kk++) {
      const int arow = wid * 16 + lr;
      const int ach = (kk * 4 + hi) ^ (arow & 7);
      bf16x8_t aqh = *(const bf16x8_t*)&Qs[0][arow][ach * 8];
      bf16x8_t aql = *(const bf16x8_t*)&Qs[1][arow][ach * 8];
#pragma unroll
      for (int n = 0; n < 4; n++) {
        const int brw = n * 16 + lr;
        const int bch = (kk * 4 + hi) ^ (brw & 7);
        bf16x8_t bkh = *(const bf16x8_t*)&Ks[0][brw][bch * 8];
        bf16x8_t bkl = *(const bf16x8_t*)&Ks[1][brw][bch * 8];
        acc[n] = __builtin_amdgcn_mfma_f32_16x16x32_bf16(aqh, bkh, acc[n], 0, 0, 0);
        acc[n] = __builtin_amdgcn_mfma_f32_16x16x32_bf16(aqh, bkl, acc[n], 0, 0, 0);
        acc[n] = __builtin_amdgcn_mfma_f32_16x16x32_bf16(aql, bkh, acc[n], 0, 0, 0);
      }
    }

    // ---- mask + online softmax (rows hi*4+j per lane) ----
    float p[4][4];   // [n][j], static indexing only
    const int qbase = b * 512 + q0 + wid * 16 + hi * 4;
#pragma unroll
    for (int j = 0; j < 4; j++) {
      float rowmax = -INFINITY;
#pragma unroll
      for (int n = 0; n < 4; n++) {
        const int mk = mask[(size_t)(qbase + j) * 512 + k0 + n * 16 + lr];
        const float sv = mk ? -1e18f : acc[n][j] * 0.125f;
        p[n][j] = sv;
        rowmax = fmaxf(rowmax, sv);
      }
#pragma unroll
      for (int off = 1; off <= 8; off <<= 1) rowmax = fmaxf(rowmax, __shfl_xor(rowmax, off));
      const float mnew = fmaxf(m_[j], rowmax);
      const float scale = expf(m_[j] - mnew);
      float rs = 0.f;
#pragma unroll
      for (int n = 0; n < 4; n++) { const float e = expf(p[n][j] - mnew); p[n][j] = e; rs += e; }
#pragma unroll
      for (int off = 1; off <= 8; off <<= 1) rs += __shfl_xor(rs, off);
      l_[j] = l_[j] * scale + rs;
      m_[j] = mnew;
#pragma unroll
      for (int nv = 0; nv < 4; nv++) accO[nv][j] *= scale;
    }

    // ---- write P planes (swizzled, wave-private rows) ----
#pragma unroll
    for (int j = 0; j < 4; j++) {
      const int qrow = wid * 16 + hi * 4 + j;
#pragma unroll
      for (int n = 0; n < 4; n++) {
        const int col = n * 16 + lr;
        const int colp = ((((col >> 3) ^ (qrow & 7)) << 3) | (col & 7));
        const __bf16 ph = (__bf16)p[n][j];
        Ps[0][qrow][colp] = ph;
        Ps[1][qrow][colp] = (__bf16)(p[n][j] - (float)ph);
      }
    }

    // ---- PV: O[16q x 64dv] += P * V (split 3x); P rows wave-private ----
#pragma unroll
    for (int kk = 0; kk < 2; kk++) {
      const int arow = wid * 16 + lr;
      const int ach = (kk * 4 + hi) ^ (arow & 7);
      bf16x8_t aph = *(const bf16x8_t*)&Ps[0][arow][ach * 8];
      bf16x8_t apl = *(const bf16x8_t*)&Ps[1][arow][ach * 8];
#pragma unroll
      for (int nv = 0; nv < 4; nv++) {
        const int brw = nv * 16 + lr;
        const int bch = (kk * 4 + hi) ^ (brw & 7);
        bf16x8_t bvh = *(const bf16x8_t*)&Vs[0][brw][bch * 8];
        bf16x8_t bvl = *(const bf16x8_t*)&Vs[1][brw][bch * 8];
        accO[nv] = __builtin_amdgcn_mfma_f32_16x16x32_bf16(aph, bvh, accO[nv], 0, 0, 0);
        accO[nv] = __builtin_amdgcn_mfma_f32_16x16x32_bf16(aph, bvl, accO[nv], 0, 0, 0);
        accO[nv] = __builtin_amdgcn_mfma_f32_16x16x32_bf16(apl, bvh, accO[nv], 0, 0, 0);
      }
    }
  }

  // epilogue: normalize and emit planes
#pragma unroll
  for (int j = 0; j < 4; j++) {
    const float inv = 1.f / l_[j];
    const size_t orow = (size_t)(b * 512 + q0 + wid * 16 + hi * 4 + j) * 512 + h * 64;
#pragma unroll
    for (int nv = 0; nv < 4; nv++) {
      const float o = accO[nv][j] * inv;
      const __bf16 hh = (__bf16)o;
      Oh[orow + nv * 16 + lr] = hh;
      Ol[orow + nv * 16 + lr] = (__bf16)(o - (float)hh);
    }
  }
}

// ---------------------------------------------------------------------------
// Cross-attention for a 16-chain chunk, emits ctxA planes.
// ---------------------------------------------------------------------------
__global__ __launch_bounds__(256) void ca_attn_kernel(
    const float* __restrict__ Qbase, const float* __restrict__ Kc,
    const float* __restrict__ Vc, const int* __restrict__ chain_map,
    const int* __restrict__ chain_mask,
    __bf16* __restrict__ Oh, __bf16* __restrict__ Ol, int c0) {
  __shared__ float ks[12][512];
  __shared__ float vs[12][512];
  const int tid = threadIdx.x;
  const int cl = blockIdx.y, c = c0 + cl, s0 = blockIdx.x * 32;
#pragma unroll
  for (int i = 0; i < 6; i++) {
    const int fi = i * 256 + tid;
    const int lrow = fi >> 7, dq = (fi & 127) << 2;
    *reinterpret_cast<float4*>(&ks[lrow][dq]) =
        *reinterpret_cast<const float4*>(&Kc[((size_t)c * 12 + lrow) * 512 + dq]);
    *reinterpret_cast<float4*>(&vs[lrow][dq]) =
        *reinterpret_cast<const float4*>(&Vc[((size_t)c * 12 + lrow) * 512 + dq]);
  }
  __syncthreads();
  const int h = tid >> 5, sl = tid & 31;
  const int s = s0 + sl;
  const int bq = chain_map[c];
  const float* qrow = &Qbase[((size_t)(bq * 512 + s)) * 512 + h * 64];
  float4 q4[16];
#pragma unroll
  for (int i = 0; i < 16; i++) q4[i] = *reinterpret_cast<const float4*>(&qrow[i * 4]);
  const int* mrow = &chain_mask[((size_t)(c * 512 + s)) * 12];
  float sc[12];
  float mx = -INFINITY;
#pragma unroll
  for (int lI = 0; lI < 12; lI++) {
    float acc = 0.f;
#pragma unroll
    for (int i = 0; i < 16; i++) {
      const float4 kv = *reinterpret_cast<const float4*>(&ks[lI][h * 64 + i * 4]);
      acc += q4[i].x * kv.x + q4[i].y * kv.y + q4[i].z * kv.z + q4[i].w * kv.w;
    }
    acc *= 0.125f;
    if (mrow[lI]) acc = -1e18f;
    sc[lI] = acc;
    mx = fmaxf(mx, acc);
  }
  float sum = 0.f;
#pragma unroll
  for (int lI = 0; lI < 12; lI++) { sc[lI] = expf(sc[lI] - mx); sum += sc[lI]; }
  const float inv = 1.f / sum;
  const size_t obase = ((size_t)(cl * 512 + s)) * 512 + h * 64;
#pragma unroll
  for (int dq = 0; dq < 16; dq++) {
    float4 ov = make_float4(0.f, 0.f, 0.f, 0.f);
#pragma unroll
    for (int lI = 0; lI < 12; lI++) {
      const float4 vv = *reinterpret_cast<const float4*>(&vs[lI][h * 64 + dq * 4]);
      ov.x += sc[lI] * vv.x; ov.y += sc[lI] * vv.y;
      ov.z += sc[lI] * vv.z; ov.w += sc[lI] * vv.w;
    }
    float vo[4] = {ov.x * inv, ov.y * inv, ov.z * inv, ov.w * inv};
    bf16x4_t hv, lv;
#pragma unroll
    for (int j = 0; j < 4; j++) {
      const __bf16 hh = (__bf16)vo[j];
      hv[j] = hh; lv[j] = (__bf16)(vo[j] - (float)hh);
    }
    *reinterpret_cast<bf16x4_t*>(&Oh[obase + dq * 4]) = hv;
    *reinterpret_cast<bf16x4_t*>(&Ol[obase + dq * 4]) = lv;
  }
}

// ---------------------------------------------------------------------------
// Running segment-max over a 16-chain chunk, planes in/out.
// ---------------------------------------------------------------------------
template <int MODE>
__global__ __launch_bounds__(256) void agg2_kernel(
    const float* __restrict__ ctxB, const int* __restrict__ chain_map,
    const int* __restrict__ chain_mask,
    __bf16* __restrict__ ch, __bf16* __restrict__ cl, int c0) {
  const int s = blockIdx.x, b = blockIdx.y, tid = threadIdx.x;
  const size_t orow = ((size_t)(b * 512 + s)) * 512;
  float v0 = -3.0e38f, v1 = -3.0e38f;
  if (MODE != 0) {
    v0 = (float)ch[orow + tid] + (float)cl[orow + tid];
    v1 = (float)ch[orow + 256 + tid] + (float)cl[orow + 256 + tid];
  }
  for (int i = 0; i < 16; i++) {
    const int c = c0 + i;
    if (chain_map[c] == b && chain_mask[((size_t)(c * 512 + s)) * 12] != 0) {
      const float* row = &ctxB[((size_t)(i * 512 + s)) * 512];
      v0 = fmaxf(v0, row[tid]);
      v1 = fmaxf(v1, row[tid + 256]);
    }
  }
  if (MODE == 2) {
    if (v0 < -1.0e38f) v0 = 0.f;
    if (v1 < -1.0e38f) v1 = 0.f;
  }
  const __bf16 h0 = (__bf16)v0, h1 = (__bf16)v1;
  ch[orow + tid] = h0;        cl[orow + tid] = (__bf16)(v0 - (float)h0);
  ch[orow + 256 + tid] = h1;  cl[orow + 256 + tid] = (__bf16)(v1 - (float)h1);
}

// ---------------------------------------------------------------------------
// Host launch
// ---------------------------------------------------------------------------
extern "C" void kernel_launch(void* const* d_in, const int* in_sizes, int n_in,
                              void* d_out, int out_size, void* d_ws, size_t ws_size,
                              hipStream_t stream) {
  const float* inputs     = (const float*)d_in[0];
  const int*   attn_mask  = (const int*)d_in[1];
  const int*   chain_map  = (const int*)d_in[2];
  const float* span       = (const float*)d_in[3];
  const int*   chain_mask = (const int*)d_in[4];
  const float* ln_g = (const float*)d_in[5];
  const float* ln_b = (const float*)d_in[6];
  const float* sa_bq = (const float*)d_in[8];
  const float* sa_bk = (const float*)d_in[10];
  const float* sa_bv = (const float*)d_in[12];
  const float* sa_bo = (const float*)d_in[14];
  const float* lc_b  = (const float*)d_in[16];
  const float* ca_bq = (const float*)d_in[18];
  const float* ca_bk = (const float*)d_in[20];
  const float* ca_bv = (const float*)d_in[22];
  const float* ca_bo = (const float*)d_in[24];
  const float* g_b   = (const float*)d_in[26];
  const float* ff_ln_g = (const float*)d_in[27];
  const float* ff_ln_b = (const float*)d_in[28];
  const float* ff_b1 = (const float*)d_in[30];
  const float* ff_b2 = (const float*)d_in[32];

  char* ws = (char*)d_ws;
  size_t off = 0;
  auto alloc = [&](size_t bytes) -> void* {
    off = (off + 255) & ~(size_t)255;
    void* p = ws + off;
    off += bytes;
    return p;
  };

  // --- weight planes: 9 pairs (qkv+caq fused into one [2048][512]) ---------
  const size_t wel[9] = {2048ull*512, 768ull*512, 512ull*512, 512ull*512,
                         512ull*512, 512ull*512, 1024ull*512, 512ull*2048, 2048ull*512};
  __bf16* WH[9]; __bf16* WL[9];
  for (int i = 0; i < 9; i++) {
    WH[i] = (__bf16*)alloc(wel[i] * 2);
    WL[i] = (__bf16*)alloc(wel[i] * 2);
  }
  WPack pack;
  pack.w[0] = {(const float*)d_in[7],  WH[0],               WL[0],               512, 512};
  pack.w[1] = {(const float*)d_in[9],  WH[0] + 512*512,     WL[0] + 512*512,     512, 512};
  pack.w[2] = {(const float*)d_in[11], WH[0] + 1024*512,    WL[0] + 1024*512,    512, 512};
  pack.w[3] = {(const float*)d_in[17], WH[0] + 1536*512,    WL[0] + 1536*512,    512, 512};
  pack.w[4] = {(const float*)d_in[15], WH[1], WL[1], 768, 512};   // lc_w
  pack.w[5] = {(const float*)d_in[19], WH[2], WL[2], 512, 512};   // ca_wk
  pack.w[6] = {(const float*)d_in[21], WH[3], WL[3], 512, 512};   // ca_wv
  pack.w[7] = {(const float*)d_in[13], WH[4], WL[4], 512, 512};   // sa_wo
  pack.w[8] = {(const float*)d_in[23], WH[5], WL[5], 512, 512};   // ca_wo
  pack.w[9] = {(const float*)d_in[25], WH[6], WL[6], 1024, 512};  // g_w
  pack.w[10] = {(const float*)d_in[29], WH[7], WL[7], 512, 2048}; // ff_w1
  pack.w[11] = {(const float*)d_in[31], WH[8], WL[8], 2048, 512}; // ff_w2

  float* bias_cat = (float*)alloc(2048 * 4);

  // --- regions -------------------------------------------------------------
  const size_t E_BSD = 8192ull * 512;
  char* R_A = (char*)alloc(E_BSD * 4);              // 16.78 MB
  char* R_B = (char*)alloc(E_BSD * 16);             // 67.11 MB = 4 parts
  __bf16* spanh = (__bf16*)alloc(1536ull * 768 * 2);
  __bf16* spanl = (__bf16*)alloc(1536ull * 768 * 2);
  __bf16* embh  = (__bf16*)alloc(1536ull * 512 * 2);
  __bf16* embl  = (__bf16*)alloc(1536ull * 512 * 2);
  float*  v_ca  = (float*)alloc(1536ull * 512 * 4);
  if (ws_size < off) return;   // fail visibly, not fault

  // R_A: x_norm planes -> sa_ctx planes -> ctxA planes -> out1 f32
  __bf16* xh = (__bf16*)R_A;           __bf16* xl = xh + E_BSD;
  __bf16* sh = xh;                     __bf16* sl = xl;      // sa_ctx planes
  __bf16* cah = xh;                    __bf16* cal = xl;     // ctxA planes
  float*  out1 = (float*)R_A;
  // R_B parts (16.78 MB each):
  //  part0: Q planes -> ctxB f32 -> inter(lo half)
  //  part1: K planes -> attn planes -> inter(hi half)
  //  part2: VT planes -> ctx planes
  //  part3: caQ f32 -> y planes
  __bf16* Qh_g = (__bf16*)R_B;                    __bf16* Ql_g = Qh_g + E_BSD;
  __bf16* Kh_g = (__bf16*)(R_B + E_BSD * 4);      __bf16* Kl_g = Kh_g + E_BSD;
  __bf16* VTh_g = (__bf16*)(R_B + E_BSD * 8);     __bf16* VTl_g = VTh_g + E_BSD;
  float*  caQ  = (float*)(R_B + E_BSD * 12);
  float*  ctxB  = (float*)R_B;
  __bf16* ah_pl = (__bf16*)(R_B + E_BSD * 4);     __bf16* al_pl = ah_pl + E_BSD;
  __bf16* cth   = (__bf16*)(R_B + E_BSD * 8);     __bf16* ctl   = cth + E_BSD;
  __bf16* yh    = (__bf16*)(R_B + E_BSD * 12);    __bf16* yl    = yh + E_BSD;
  __bf16* ih    = (__bf16*)R_B;                   __bf16* il    = ih + 4096ull * 2048;
  float* k_ca = (float*)spanh;                    // span planes dead by then
  float* dout = (float*)d_out;
  const int KBIG = 1 << 30;
  const float* Z = nullptr;
  const __bf16* ZB = nullptr;
  __bf16* ZM = nullptr;

  auto gemm = [&](int EPI, const __bf16* a0h, const __bf16* a0l,
                  const __bf16* a1h, const __bf16* a1l, int lda, int ksplit,
                  int wi, int K, const float* bias,
                  float* cf, __bf16* chp, __bf16* clp,
                  __bf16* c2h, __bf16* c2l, __bf16* c3h, __bf16* c3l,
                  int ldc, size_t secs,
                  const __bf16* E0h, const __bf16* E0l,
                  const __bf16* E1h, const __bf16* E1l, const float* E2,
                  int M, int N) {
    dim3 grid(N / 128, M / 128);
    switch (EPI) {
      case 0: gemm2_kernel<0><<<grid, 256, 0, stream>>>(a0h, a0l, a1h, a1l, lda, ksplit, WH[wi], WL[wi], K, bias, cf, chp, clp, c2h, c2l, c3h, c3l, ldc, secs, E0h, E0l, E1h, E1l, E2); break;
      case 1: gemm2_kernel<1><<<grid, 256, 0, stream>>>(a0h, a0l, a1h, a1l, lda, ksplit, WH[wi], WL[wi], K, bias, cf, chp, clp, c2h, c2l, c3h, c3l, ldc, secs, E0h, E0l, E1h, E1l, E2); break;
      case 2: gemm2_kernel<2><<<grid, 256, 0, stream>>>(a0h, a0l, a1h, a1l, lda, ksplit, WH[wi], WL[wi], K, bias, cf, chp, clp, c2h, c2l, c3h, c3l, ldc, secs, E0h, E0l, E1h, E1l, E2); break;
      case 3: gemm2_kernel<3><<<grid, 256, 0, stream>>>(a0h, a0l, a1h, a1l, lda, ksplit, WH[wi], WL[wi], K, bias, cf, chp, clp, c2h, c2l, c3h, c3l, ldc, secs, E0h, E0l, E1h, E1l, E2); break;
      case 4: gemm2_kernel<4><<<grid, 256, 0, stream>>>(a0h, a0l, a1h, a1l, lda, ksplit, WH[wi], WL[wi], K, bias, cf, chp, clp, c2h, c2l, c3h, c3l, ldc, secs, E0h, E0l, E1h, E1l, E2); break;
      case 5: gemm2_kernel<5><<<grid, 256, 0, stream>>>(a0h, a0l, a1h, a1l, lda, ksplit, WH[wi], WL[wi], K, bias, cf, chp, clp, c2h, c2l, c3h, c3l, ldc, secs, E0h, E0l, E1h, E1l, E2); break;
    }
  };

  prep_weights_kernel<<<dim3(64, 12), 256, 0, stream>>>(pack);
  bias_cat_kernel<<<8, 256, 0, stream>>>(sa_bq, sa_bk, sa_bv, ca_bq, bias_cat);
  split_kernel<<<1152, 256, 0, stream>>>(span, spanh, spanl, 1536 * 768 / 4);
  ln_split_kernel<<<2048, 256, 0, stream>>>(inputs, ln_g, ln_b, xh, xl);

  // fused QKV + CA-Q projection: Q/K planes, V transposed planes, caQ f32
  gemm(5, xh, xl, xh, xl, 512, KBIG, 0, 512, bias_cat,
       caQ, Qh_g, Ql_g, Kh_g, Kl_g, VTh_g, VTl_g, 512, 0,
       ZB, ZB, ZB, ZB, Z, 8192, 2048);

  sa_attn_mfma_kernel<<<dim3(8, 8, 16), 256, 0, stream>>>(
      Qh_g, Ql_g, Kh_g, Kl_g, VTh_g, VTl_g, attn_mask, sh, sl);
  // sa_wo -> attn planes (part1; K planes dead after sa_attn)
  gemm(1, sh, sl, sh, sl, 512, KBIG, 4, 512, sa_bo,
       nullptr, ah_pl, al_pl, ZM, ZM, ZM, ZM, 512, 0, ZB, ZB, ZB, ZB, Z, 8192, 512);

  // cross-attention K/V precompute
  gemm(1, spanh, spanl, spanh, spanl, 768, KBIG, 1, 768, lc_b,
       nullptr, embh, embl, ZM, ZM, ZM, ZM, 512, 0, ZB, ZB, ZB, ZB, Z, 1536, 512);
  gemm(0, embh, embl, embh, embl, 512, KBIG, 2, 512, ca_bk,
       k_ca, nullptr, nullptr, ZM, ZM, ZM, ZM, 512, 0, ZB, ZB, ZB, ZB, Z, 1536, 512);
  gemm(0, embh, embl, embh, embl, 512, KBIG, 3, 512, ca_bv,
       v_ca, nullptr, nullptr, ZM, ZM, ZM, ZM, 512, 0, ZB, ZB, ZB, ZB, Z, 1536, 512);

  // CA in 8 chunks of 16 chains; running segment-max into ctx planes
  for (int chk = 0; chk < 8; chk++) {
    const int c0 = chk * 16;
    ca_attn_kernel<<<dim3(16, 16), 256, 0, stream>>>(caQ, k_ca, v_ca, chain_map, chain_mask, cah, cal, c0);
    gemm(0, cah, cal, cah, cal, 512, KBIG, 5, 512, ca_bo,
         ctxB, nullptr, nullptr, ZM, ZM, ZM, ZM, 512, 0, ZB, ZB, ZB, ZB, Z, 8192, 512);
    if (chk == 0)      agg2_kernel<0><<<dim3(512, 16), 256, 0, stream>>>(ctxB, chain_map, chain_mask, cth, ctl, c0);
    else if (chk == 7) agg2_kernel<2><<<dim3(512, 16), 256, 0, stream>>>(ctxB, chain_map, chain_mask, cth, ctl, c0);
    else               agg2_kernel<1><<<dim3(512, 16), 256, 0, stream>>>(ctxB, chain_map, chain_mask, cth, ctl, c0);
  }

  // gate: A = [attn planes | ctx planes], epilogue z*a+(1-z)*c+inputs -> out1
  gemm(3, ah_pl, al_pl, cth, ctl, 512, 512, 6, 1024, g_b,
       out1, nullptr, nullptr, ZM, ZM, ZM, ZM, 512, 0,
       ah_pl, al_pl, cth, ctl, inputs, 8192, 512);

  // feed-forward
  ln_split_kernel<<<2048, 256, 0, stream>>>(out1, ff_ln_g, ff_ln_b, yh, yl);
  for (int r0 = 0; r0 < 8192; r0 += 4096) {
    gemm(2, yh + (size_t)r0 * 512, yl + (size_t)r0 * 512,
         yh + (size_t)r0 * 512, yl + (size_t)r0 * 512, 512, KBIG, 7, 512, ff_b1,
         nullptr, ih, il, ZM, ZM, ZM, ZM, 2048, 512, ZB, ZB, ZB, ZB, Z, 4096, 2048);
    gemm(4, ih, il, ih, il, 2048, KBIG, 8, 2048, ff_b2,
         dout + (size_t)r0 * 512, nullptr, nullptr, ZM, ZM, ZM, ZM, 512, 0,
         ZB, ZB, ZB, ZB, out1 + (size_t)r0 * 512, 4096, 512);
  }
}

// Round 8
// 1125.110 us; speedup vs baseline: 2.0560x; 1.0628x over previous
//
#include <hip/hip_runtime.h>
#include <hip/hip_bf16.h>
#include <math.h>

typedef float f32x4_t __attribute__((ext_vector_type(4)));
typedef __bf16 bf16x8_t __attribute__((ext_vector_type(8)));
typedef __bf16 bf16x4_t __attribute__((ext_vector_type(4)));

__device__ __forceinline__ void gload16(const void* g, void* l) {
  __builtin_amdgcn_global_load_lds((const __attribute__((address_space(1))) void*)g,
                                   (__attribute__((address_space(3))) void*)l, 16, 0, 0);
}

// ---------------------------------------------------------------------------
// Weight prep: fp32 W[K][N] -> bf16 hi/lo planes, transposed to [N][K].
// ---------------------------------------------------------------------------
struct WDesc { const float* src; __bf16* hi; __bf16* lo; int K; int N; };
struct WPack { WDesc w[12]; };

__global__ __launch_bounds__(256) void prep_weights_kernel(WPack p) {
  WDesc d = p.w[blockIdx.y];
  const int tilesN = d.N >> 6;
  const int ntiles = (d.K >> 6) * tilesN;
  __shared__ float tile[64][65];
  const int tid = threadIdx.x;
  const int r = tid >> 4, cq = (tid & 15) << 2;
  const int c = tid >> 4, rq = (tid & 15) << 2;
  for (int t = blockIdx.x; t < ntiles; t += gridDim.x) {
    const int tk = t / tilesN, tn = t - tk * tilesN;
    const int k0 = tk << 6, n0 = tn << 6;
#pragma unroll
    for (int i = 0; i < 4; i++) {
      const float4 v = *reinterpret_cast<const float4*>(
          &d.src[(size_t)(k0 + r + i * 16) * d.N + n0 + cq]);
      tile[r + i * 16][cq] = v.x; tile[r + i * 16][cq + 1] = v.y;
      tile[r + i * 16][cq + 2] = v.z; tile[r + i * 16][cq + 3] = v.w;
    }
    __syncthreads();
#pragma unroll
    for (int i = 0; i < 4; i++) {
      const int cc = c + i * 16;
      const float v0 = tile[rq][cc], v1 = tile[rq + 1][cc];
      const float v2 = tile[rq + 2][cc], v3 = tile[rq + 3][cc];
      const __bf16 h0 = (__bf16)v0, h1 = (__bf16)v1, h2 = (__bf16)v2, h3 = (__bf16)v3;
      bf16x4_t hv = {h0, h1, h2, h3};
      bf16x4_t lv = {(__bf16)(v0 - (float)h0), (__bf16)(v1 - (float)h1),
                     (__bf16)(v2 - (float)h2), (__bf16)(v3 - (float)h3)};
      *reinterpret_cast<bf16x4_t*>(&d.hi[(size_t)(n0 + cc) * d.K + k0 + rq]) = hv;
      *reinterpret_cast<bf16x4_t*>(&d.lo[(size_t)(n0 + cc) * d.K + k0 + rq]) = lv;
    }
    __syncthreads();
  }
}

__global__ __launch_bounds__(256) void bias_cat_kernel(
    const float* __restrict__ b0, const float* __restrict__ b1,
    const float* __restrict__ b2, const float* __restrict__ b3,
    float* __restrict__ out) {
  const int t = blockIdx.x * 256 + threadIdx.x;   // grid 8 -> 2048
  const float* s = t < 512 ? b0 : t < 1024 ? b1 : t < 1536 ? b2 : b3;
  out[t] = s[t & 511];
}

// fp32 -> hi/lo bf16 planes (for span_embeddings)
__global__ __launch_bounds__(256) void split_kernel(
    const float* __restrict__ x, __bf16* __restrict__ h, __bf16* __restrict__ l, int nq) {
  const int i = blockIdx.x * 256 + threadIdx.x;
  if (i >= nq) return;
  const float4 v = reinterpret_cast<const float4*>(x)[i];
  const __bf16 h0 = (__bf16)v.x, h1 = (__bf16)v.y, h2 = (__bf16)v.z, h3 = (__bf16)v.w;
  bf16x4_t hv = {h0, h1, h2, h3};
  bf16x4_t lv = {(__bf16)(v.x - (float)h0), (__bf16)(v.y - (float)h1),
                 (__bf16)(v.z - (float)h2), (__bf16)(v.w - (float)h3)};
  reinterpret_cast<bf16x4_t*>(h)[i] = hv;
  reinterpret_cast<bf16x4_t*>(l)[i] = lv;
}

// umax fill: monotone-encoded -3e38 sentinel, uint4 per thread
__global__ __launch_bounds__(256) void fill_umax_kernel(unsigned* __restrict__ p) {
  const unsigned e = ~__float_as_uint(-3.0e38f);
  reinterpret_cast<uint4*>(p)[blockIdx.x * 256 + threadIdx.x] = make_uint4(e, e, e, e);
}

// decode umax -> ctx planes, with -inf -> 0 fix
__global__ __launch_bounds__(256) void decode_umax_kernel(
    const unsigned* __restrict__ u, __bf16* __restrict__ ch, __bf16* __restrict__ cl) {
  const int i = blockIdx.x * 256 + threadIdx.x;   // x4 elems
  const uint4 v = reinterpret_cast<const uint4*>(u)[i];
  unsigned a[4] = {v.x, v.y, v.z, v.w};
  bf16x4_t hv, lv;
#pragma unroll
  for (int j = 0; j < 4; j++) {
    const unsigned bits = (a[j] & 0x80000000u) ? (a[j] & 0x7FFFFFFFu) : ~a[j];
    float f = __uint_as_float(bits);
    if (f < -1.0e38f) f = 0.f;
    const __bf16 hh = (__bf16)f;
    hv[j] = hh; lv[j] = (__bf16)(f - (float)hh);
  }
  reinterpret_cast<bf16x4_t*>(ch)[i] = hv;
  reinterpret_cast<bf16x4_t*>(cl)[i] = lv;
}

// ---------------------------------------------------------------------------
// LayerNorm over D=512, one wave per row, emits hi/lo bf16 planes
// ---------------------------------------------------------------------------
__global__ __launch_bounds__(256) void ln_split_kernel(
    const float* __restrict__ x, const float* __restrict__ g,
    const float* __restrict__ bb, __bf16* __restrict__ yh, __bf16* __restrict__ yl) {
  const int row = blockIdx.x * 4 + (threadIdx.x >> 6);
  const int lane = threadIdx.x & 63;
  const float* xr = x + (size_t)row * 512;
  float4 a = *reinterpret_cast<const float4*>(&xr[lane * 8]);
  float4 b4 = *reinterpret_cast<const float4*>(&xr[lane * 8 + 4]);
  float v[8] = {a.x, a.y, a.z, a.w, b4.x, b4.y, b4.z, b4.w};
  float s = 0.f;
#pragma unroll
  for (int j = 0; j < 8; j++) s += v[j];
#pragma unroll
  for (int off = 1; off < 64; off <<= 1) s += __shfl_xor(s, off);
  const float mean = s * (1.f / 512.f);
  float sq = 0.f;
#pragma unroll
  for (int j = 0; j < 8; j++) { v[j] -= mean; sq += v[j] * v[j]; }
#pragma unroll
  for (int off = 1; off < 64; off <<= 1) sq += __shfl_xor(sq, off);
  const float inv = rsqrtf(sq * (1.f / 512.f) + 1e-6f);
  bf16x8_t hv, lv;
#pragma unroll
  for (int j = 0; j < 8; j++) {
    const float o = v[j] * inv * g[lane * 8 + j] + bb[lane * 8 + j];
    const __bf16 h = (__bf16)o;
    hv[j] = h; lv[j] = (__bf16)(o - (float)h);
  }
  *reinterpret_cast<bf16x8_t*>(&yh[(size_t)row * 512 + lane * 8]) = hv;
  *reinterpret_cast<bf16x8_t*>(&yl[(size_t)row * 512 + lane * 8]) = lv;
}

// ---------------------------------------------------------------------------
// Split-bf16 MFMA GEMM v3: 512 threads / 8 waves, 128x128 tile, BK=64.
// Each wave computes 64x32 (acc[4][2]); staging: wave w stages half
// (w&1) of plane (w>>1) via global_load_lds with XOR-swizzled source.
// EPI: 0 f32  1 planes  2 planes+relu  3 gate  4 f32+residual
//      5 qkvq (Q/K planes, V transposed planes, caQ f32)
//      6 atomic segment-max (Cf = umax buffer, cmap/cmask/c0 used)
// ---------------------------------------------------------------------------
template <int EPI>
__global__ __launch_bounds__(512, 4) void gemm2_kernel(
    const __bf16* __restrict__ A0h, const __bf16* __restrict__ A0l,
    const __bf16* __restrict__ A1h, const __bf16* __restrict__ A1l,
    int lda, int ksplit,
    const __bf16* __restrict__ Bh, const __bf16* __restrict__ Bl, int K,
    const float* __restrict__ bias,
    float* __restrict__ Cf, __bf16* __restrict__ Ch, __bf16* __restrict__ Cl,
    __bf16* __restrict__ C2h, __bf16* __restrict__ C2l,
    __bf16* __restrict__ C3h, __bf16* __restrict__ C3l,
    int ldc, size_t sec_stride,
    const __bf16* __restrict__ e0h, const __bf16* __restrict__ e0l,
    const __bf16* __restrict__ e1h, const __bf16* __restrict__ e1l,
    const float* __restrict__ e2,
    const int* __restrict__ cmap, const int* __restrict__ cmask, int c0) {
  __shared__ __bf16 lds[4][128][64];   // Ah, Al, Bh, Bl
  const int tid = threadIdx.x;
  const int wave = tid >> 6, lane = tid & 63;
  const int brow = blockIdx.y * 128, bcol = blockIdx.x * 128;
  const int wr = (wave >> 2) * 64, wc = (wave & 3) * 32;
  const int lr = lane & 15, hi = lane >> 4;
  const int s_row = lane >> 3;
  const int s_sc = (lane & 7) ^ s_row;
  const int pl_id = wave >> 1;              // 0:Ah 1:Al 2:Bh 3:Bl
  const int half = (wave & 1) * 64;
  const int trow_base = (pl_id < 2 ? brow : bcol) + half;

  f32x4_t acc[4][2] = {};

  for (int k0 = 0; k0 < K; k0 += 64) {
    const __bf16* ah = A0h; const __bf16* al = A0l; int kc = k0;
    if (k0 >= ksplit) { ah = A1h; al = A1l; kc = k0 - ksplit; }
    const __bf16* plane = pl_id == 0 ? ah : pl_id == 1 ? al : pl_id == 2 ? Bh : Bl;
    const int pl_lda = pl_id < 2 ? lda : K;
    const int pk = pl_id < 2 ? kc : k0;
    const __bf16* src = plane + (size_t)(trow_base + s_row) * pl_lda + pk + s_sc * 8;
    __bf16* ldst = &lds[pl_id][half][0];
#pragma unroll
    for (int i = 0; i < 8; i++)
      gload16(src + (size_t)i * 8 * pl_lda, ldst + i * 8 * 64);
    __syncthreads();
#pragma unroll
    for (int kk = 0; kk < 2; kk++) {
      bf16x8_t afh[4], afl[4], bfh[2], bfl[2];
#pragma unroll
      for (int m = 0; m < 4; m++) {
        const int row = wr + m * 16 + lr;
        const int ch = (kk * 4 + hi) ^ (row & 7);
        afh[m] = *(const bf16x8_t*)((const char*)&lds[0][0][0] + row * 128 + ch * 16);
        afl[m] = *(const bf16x8_t*)((const char*)&lds[1][0][0] + row * 128 + ch * 16);
      }
#pragma unroll
      for (int n = 0; n < 2; n++) {
        const int row = wc + n * 16 + lr;
        const int ch = (kk * 4 + hi) ^ (row & 7);
        bfh[n] = *(const bf16x8_t*)((const char*)&lds[2][0][0] + row * 128 + ch * 16);
        bfl[n] = *(const bf16x8_t*)((const char*)&lds[3][0][0] + row * 128 + ch * 16);
      }
#pragma unroll
      for (int m = 0; m < 4; m++)
#pragma unroll
        for (int n = 0; n < 2; n++) {
          acc[m][n] = __builtin_amdgcn_mfma_f32_16x16x32_bf16(afh[m], bfh[n], acc[m][n], 0, 0, 0);
          acc[m][n] = __builtin_amdgcn_mfma_f32_16x16x32_bf16(afh[m], bfl[n], acc[m][n], 0, 0, 0);
          acc[m][n] = __builtin_amdgcn_mfma_f32_16x16x32_bf16(afl[m], bfh[n], acc[m][n], 0, 0, 0);
        }
    }
    __syncthreads();
  }

#pragma unroll
  for (int m = 0; m < 4; m++) {
#pragma unroll
    for (int n = 0; n < 2; n++) {
      const int colg = bcol + wc + n * 16 + lr;
      const size_t cb = (size_t)(colg >> 9) * sec_stride + (colg & 511);
      const float bv = bias[colg];
#pragma unroll
      for (int r = 0; r < 4; r++) {
        const int row = brow + wr + m * 16 + hi * 4 + r;
        float v = acc[m][n][r] + bv;
        if constexpr (EPI == 0) {
          Cf[cb + (size_t)row * ldc] = v;
        } else if constexpr (EPI == 1) {
          const __bf16 h = (__bf16)v;
          Ch[cb + (size_t)row * ldc] = h;
          Cl[cb + (size_t)row * ldc] = (__bf16)(v - (float)h);
        } else if constexpr (EPI == 2) {
          v = fmaxf(v, 0.f);
          const __bf16 h = (__bf16)v;
          Ch[cb + (size_t)row * ldc] = h;
          Cl[cb + (size_t)row * ldc] = (__bf16)(v - (float)h);
        } else if constexpr (EPI == 3) {
          const float z = 1.f / (1.f + expf(-v));
          const size_t ei = (size_t)row * 512 + colg;
          const float a = (float)e0h[ei] + (float)e0l[ei];
          const float c = (float)e1h[ei] + (float)e1l[ei];
          Cf[cb + (size_t)row * ldc] = z * a + (1.f - z) * c + e2[ei];
        } else if constexpr (EPI == 4) {
          Cf[cb + (size_t)row * ldc] = v + e2[(size_t)row * 512 + colg];
        } else if constexpr (EPI == 5) {
          const int sec = colg >> 9, cc = colg & 511;
          const __bf16 h = (__bf16)v;
          const __bf16 lo = (__bf16)(v - (float)h);
          if (sec == 0)      { Ch[(size_t)row * 512 + cc] = h;  Cl[(size_t)row * 512 + cc] = lo; }
          else if (sec == 1) { C2h[(size_t)row * 512 + cc] = h; C2l[(size_t)row * 512 + cc] = lo; }
          else if (sec == 2) {
            const int bb2 = row >> 9, ss = row & 511, hh2 = cc >> 6, dv = cc & 63;
            const size_t va = ((size_t)((bb2 * 8 + hh2) * 64 + dv)) * 512 + ss;
            C3h[va] = h; C3l[va] = lo;
          } else {
            Cf[(size_t)row * 512 + cc] = v;
          }
        } else if constexpr (EPI == 6) {
          const int clc = row >> 9, s = row & 511;
          if (cmask[((size_t)((c0 + clc) * 512 + s)) * 12] != 0) {
            const int b = cmap[c0 + clc];
            const unsigned bits = __float_as_uint(v);
            const unsigned enc = (bits & 0x80000000u) ? ~bits : (bits | 0x80000000u);
            atomicMax((unsigned*)Cf + ((size_t)(b * 512 + s)) * 512 + colg, enc);
          }
        }
      }
    }
  }
}

// ---------------------------------------------------------------------------
// MFMA flash self-attention (unchanged).
// ---------------------------------------------------------------------------
__global__ __launch_bounds__(256, 2) void sa_attn_mfma_kernel(
    const __bf16* __restrict__ Qh_g, const __bf16* __restrict__ Ql_g,
    const __bf16* __restrict__ Kh_g, const __bf16* __restrict__ Kl_g,
    const __bf16* __restrict__ Vth_g, const __bf16* __restrict__ Vtl_g,
    const int* __restrict__ mask,
    __bf16* __restrict__ Oh, __bf16* __restrict__ Ol) {
  __shared__ __bf16 Qs[2][64][64];
  __shared__ __bf16 Ks[2][64][64];
  __shared__ __bf16 Vs[2][64][64];
  __shared__ __bf16 Ps[2][64][64];
  const int tid = threadIdx.x;
  const int wid = tid >> 6, lane = tid & 63;
  const int q0 = blockIdx.x * 64;
  const int h = blockIdx.y, b = blockIdx.z;
  const int lr = lane & 15, hi = lane >> 4;
  const int s_row = lane >> 3;
  const int s_sc = (lane & 7) ^ s_row;

  {
    const __bf16* qp = (wid < 2 ? Qh_g : Ql_g);
    const int pl = (wid < 2 ? 0 : 1);
    const int r0 = (wid & 1) * 32;
    const __bf16* src = qp + (size_t)(b * 512 + q0 + r0 + s_row) * 512 + h * 64 + s_sc * 8;
#pragma unroll
    for (int i = 0; i < 4; i++)
      gload16(src + (size_t)i * 8 * 512, &Qs[pl][r0 + i * 8][0]);
  }
  f32x4_t accO[4] = {};
  float m_[4], l_[4];
#pragma unroll
  for (int j = 0; j < 4; j++) { m_[j] = -INFINITY; l_[j] = 0.f; }

  for (int kt = 0; kt < 8; kt++) {
    const int k0 = kt * 64;
    __syncthreads();
    {
      const __bf16* plane = wid == 0 ? Kh_g : wid == 1 ? Kl_g : wid == 2 ? Vth_g : Vtl_g;
      size_t srow; int scol;
      if (wid < 2) { srow = (size_t)(b * 512 + k0 + s_row);     scol = h * 64; }
      else         { srow = (size_t)((b * 8 + h) * 64 + s_row); scol = k0; }
      const __bf16* src = plane + srow * 512 + scol + s_sc * 8;
      __bf16* dst0 = (wid == 0) ? &Ks[0][0][0] : (wid == 1) ? &Ks[1][0][0]
                   : (wid == 2) ? &Vs[0][0][0] : &Vs[1][0][0];
#pragma unroll
      for (int i = 0; i < 8; i++)
        gload16(src + (size_t)i * 8 * 512, dst0 + i * 8 * 64);
    }
    __syncthreads();

    f32x4_t acc[4] = {};
#pragma unroll
    for (int kk = 0; kk < 2; kk++) {
      const int arow = wid * 16 + lr;
      const int ach = (kk * 4 + hi) ^ (arow & 7);
      bf16x8_t aqh = *(const bf16x8_t*)&Qs[0][arow][ach * 8];
      bf16x8_t aql = *(const bf16x8_t*)&Qs[1][arow][ach * 8];
#pragma unroll
      for (int n = 0; n < 4; n++) {
        const int brw = n * 16 + lr;
        const int bch = (kk * 4 + hi) ^ (brw & 7);
        bf16x8_t bkh = *(const bf16x8_t*)&Ks[0][brw][bch * 8];
        bf16x8_t bkl = *(const bf16x8_t*)&Ks[1][brw][bch * 8];
        acc[n] = __builtin_amdgcn_mfma_f32_16x16x32_bf16(aqh, bkh, acc[n], 0, 0, 0);
        acc[n] = __builtin_amdgcn_mfma_f32_16x16x32_bf16(aqh, bkl, acc[n], 0, 0, 0);
        acc[n] = __builtin_amdgcn_mfma_f32_16x16x32_bf16(aql, bkh, acc[n], 0, 0, 0);
      }
    }

    float p[4][4];
    const int qbase = b * 512 + q0 + wid * 16 + hi * 4;
#pragma unroll
    for (int j = 0; j < 4; j++) {
      float rowmax = -INFINITY;
#pragma unroll
      for (int n = 0; n < 4; n++) {
        const int mk = mask[(size_t)(qbase + j) * 512 + k0 + n * 16 + lr];
        const float sv = mk ? -1e18f : acc[n][j] * 0.125f;
        p[n][j] = sv;
        rowmax = fmaxf(rowmax, sv);
      }
#pragma unroll
      for (int off = 1; off <= 8; off <<= 1) rowmax = fmaxf(rowmax, __shfl_xor(rowmax, off));
      const float mnew = fmaxf(m_[j], rowmax);
      const float scale = expf(m_[j] - mnew);
      float rs = 0.f;
#pragma unroll
      for (int n = 0; n < 4; n++) { const float e = expf(p[n][j] - mnew); p[n][j] = e; rs += e; }
#pragma unroll
      for (int off = 1; off <= 8; off <<= 1) rs += __shfl_xor(rs, off);
      l_[j] = l_[j] * scale + rs;
      m_[j] = mnew;
#pragma unroll
      for (int nv = 0; nv < 4; nv++) accO[nv][j] *= scale;
    }

#pragma unroll
    for (int j = 0; j < 4; j++) {
      const int qrow = wid * 16 + hi * 4 + j;
#pragma unroll
      for (int n = 0; n < 4; n++) {
        const int col = n * 16 + lr;
        const int colp = ((((col >> 3) ^ (qrow & 7)) << 3) | (col & 7));
        const __bf16 ph = (__bf16)p[n][j];
        Ps[0][qrow][colp] = ph;
        Ps[1][qrow][colp] = (__bf16)(p[n][j] - (float)ph);
      }
    }

#pragma unroll
    for (int kk = 0; kk < 2; kk++) {
      const int arow = wid * 16 + lr;
      const int ach = (kk * 4 + hi) ^ (arow & 7);
      bf16x8_t aph = *(const bf16x8_t*)&Ps[0][arow][ach * 8];
      bf16x8_t apl = *(const bf16x8_t*)&Ps[1][arow][ach * 8];
#pragma unroll
      for (int nv = 0; nv < 4; nv++) {
        const int brw = nv * 16 + lr;
        const int bch = (kk * 4 + hi) ^ (brw & 7);
        bf16x8_t bvh = *(const bf16x8_t*)&Vs[0][brw][bch * 8];
        bf16x8_t bvl = *(const bf16x8_t*)&Vs[1][brw][bch * 8];
        accO[nv] = __builtin_amdgcn_mfma_f32_16x16x32_bf16(aph, bvh, accO[nv], 0, 0, 0);
        accO[nv] = __builtin_amdgcn_mfma_f32_16x16x32_bf16(aph, bvl, accO[nv], 0, 0, 0);
        accO[nv] = __builtin_amdgcn_mfma_f32_16x16x32_bf16(apl, bvh, accO[nv], 0, 0, 0);
      }
    }
  }

#pragma unroll
  for (int j = 0; j < 4; j++) {
    const float inv = 1.f / l_[j];
    const size_t orow = (size_t)(b * 512 + q0 + wid * 16 + hi * 4 + j) * 512 + h * 64;
#pragma unroll
    for (int nv = 0; nv < 4; nv++) {
      const float o = accO[nv][j] * inv;
      const __bf16 hh = (__bf16)o;
      Oh[orow + nv * 16 + lr] = hh;
      Ol[orow + nv * 16 + lr] = (__bf16)(o - (float)hh);
    }
  }
}

// ---------------------------------------------------------------------------
// Cross-attention for a 16-chain chunk, emits ctxA planes (unchanged).
// ---------------------------------------------------------------------------
__global__ __launch_bounds__(256) void ca_attn_kernel(
    const float* __restrict__ Qbase, const float* __restrict__ Kc,
    const float* __restrict__ Vc, const int* __restrict__ chain_map,
    const int* __restrict__ chain_mask,
    __bf16* __restrict__ Oh, __bf16* __restrict__ Ol, int c0) {
  __shared__ float ks[12][512];
  __shared__ float vs[12][512];
  const int tid = threadIdx.x;
  const int cl = blockIdx.y, c = c0 + cl, s0 = blockIdx.x * 32;
#pragma unroll
  for (int i = 0; i < 6; i++) {
    const int fi = i * 256 + tid;
    const int lrow = fi >> 7, dq = (fi & 127) << 2;
    *reinterpret_cast<float4*>(&ks[lrow][dq]) =
        *reinterpret_cast<const float4*>(&Kc[((size_t)c * 12 + lrow) * 512 + dq]);
    *reinterpret_cast<float4*>(&vs[lrow][dq]) =
        *reinterpret_cast<const float4*>(&Vc[((size_t)c * 12 + lrow) * 512 + dq]);
  }
  __syncthreads();
  const int h = tid >> 5, sl = tid & 31;
  const int s = s0 + sl;
  const int bq = chain_map[c];
  const float* qrow = &Qbase[((size_t)(bq * 512 + s)) * 512 + h * 64];
  float4 q4[16];
#pragma unroll
  for (int i = 0; i < 16; i++) q4[i] = *reinterpret_cast<const float4*>(&qrow[i * 4]);
  const int* mrow = &chain_mask[((size_t)(c * 512 + s)) * 12];
  float sc[12];
  float mx = -INFINITY;
#pragma unroll
  for (int lI = 0; lI < 12; lI++) {
    float acc = 0.f;
#pragma unroll
    for (int i = 0; i < 16; i++) {
      const float4 kv = *reinterpret_cast<const float4*>(&ks[lI][h * 64 + i * 4]);
      acc += q4[i].x * kv.x + q4[i].y * kv.y + q4[i].z * kv.z + q4[i].w * kv.w;
    }
    acc *= 0.125f;
    if (mrow[lI]) acc = -1e18f;
    sc[lI] = acc;
    mx = fmaxf(mx, acc);
  }
  float sum = 0.f;
#pragma unroll
  for (int lI = 0; lI < 12; lI++) { sc[lI] = expf(sc[lI] - mx); sum += sc[lI]; }
  const float inv = 1.f / sum;
  const size_t obase = ((size_t)(cl * 512 + s)) * 512 + h * 64;
#pragma unroll
  for (int dq = 0; dq < 16; dq++) {
    float4 ov = make_float4(0.f, 0.f, 0.f, 0.f);
#pragma unroll
    for (int lI = 0; lI < 12; lI++) {
      const float4 vv = *reinterpret_cast<const float4*>(&vs[lI][h * 64 + dq * 4]);
      ov.x += sc[lI] * vv.x; ov.y += sc[lI] * vv.y;
      ov.z += sc[lI] * vv.z; ov.w += sc[lI] * vv.w;
    }
    float vo[4] = {ov.x * inv, ov.y * inv, ov.z * inv, ov.w * inv};
    bf16x4_t hv, lv;
#pragma unroll
    for (int j = 0; j < 4; j++) {
      const __bf16 hh = (__bf16)vo[j];
      hv[j] = hh; lv[j] = (__bf16)(vo[j] - (float)hh);
    }
    *reinterpret_cast<bf16x4_t*>(&Oh[obase + dq * 4]) = hv;
    *reinterpret_cast<bf16x4_t*>(&Ol[obase + dq * 4]) = lv;
  }
}

// ---------------------------------------------------------------------------
// Host launch
// ---------------------------------------------------------------------------
extern "C" void kernel_launch(void* const* d_in, const int* in_sizes, int n_in,
                              void* d_out, int out_size, void* d_ws, size_t ws_size,
                              hipStream_t stream) {
  const float* inputs     = (const float*)d_in[0];
  const int*   attn_mask  = (const int*)d_in[1];
  const int*   chain_map  = (const int*)d_in[2];
  const float* span       = (const float*)d_in[3];
  const int*   chain_mask = (const int*)d_in[4];
  const float* ln_g = (const float*)d_in[5];
  const float* ln_b = (const float*)d_in[6];
  const float* sa_bq = (const float*)d_in[8];
  const float* sa_bk = (const float*)d_in[10];
  const float* sa_bv = (const float*)d_in[12];
  const float* sa_bo = (const float*)d_in[14];
  const float* lc_b  = (const float*)d_in[16];
  const float* ca_bq = (const float*)d_in[18];
  const float* ca_bk = (const float*)d_in[20];
  const float* ca_bv = (const float*)d_in[22];
  const float* ca_bo = (const float*)d_in[24];
  const float* g_b   = (const float*)d_in[26];
  const float* ff_ln_g = (const float*)d_in[27];
  const float* ff_ln_b = (const float*)d_in[28];
  const float* ff_b1 = (const float*)d_in[30];
  const float* ff_b2 = (const float*)d_in[32];

  char* ws = (char*)d_ws;
  size_t off = 0;
  auto alloc = [&](size_t bytes) -> void* {
    off = (off + 255) & ~(size_t)255;
    void* p = ws + off;
    off += bytes;
    return p;
  };

  // --- weight planes ------------------------------------------------------
  const size_t wel[9] = {2048ull*512, 768ull*512, 512ull*512, 512ull*512,
                         512ull*512, 512ull*512, 1024ull*512, 512ull*2048, 2048ull*512};
  __bf16* WH[9]; __bf16* WL[9];
  for (int i = 0; i < 9; i++) {
    WH[i] = (__bf16*)alloc(wel[i] * 2);
    WL[i] = (__bf16*)alloc(wel[i] * 2);
  }
  WPack pack;
  pack.w[0] = {(const float*)d_in[7],  WH[0],               WL[0],               512, 512};
  pack.w[1] = {(const float*)d_in[9],  WH[0] + 512*512,     WL[0] + 512*512,     512, 512};
  pack.w[2] = {(const float*)d_in[11], WH[0] + 1024*512,    WL[0] + 1024*512,    512, 512};
  pack.w[3] = {(const float*)d_in[17], WH[0] + 1536*512,    WL[0] + 1536*512,    512, 512};
  pack.w[4] = {(const float*)d_in[15], WH[1], WL[1], 768, 512};
  pack.w[5] = {(const float*)d_in[19], WH[2], WL[2], 512, 512};
  pack.w[6] = {(const float*)d_in[21], WH[3], WL[3], 512, 512};
  pack.w[7] = {(const float*)d_in[13], WH[4], WL[4], 512, 512};
  pack.w[8] = {(const float*)d_in[23], WH[5], WL[5], 512, 512};
  pack.w[9] = {(const float*)d_in[25], WH[6], WL[6], 1024, 512};
  pack.w[10] = {(const float*)d_in[29], WH[7], WL[7], 512, 2048};
  pack.w[11] = {(const float*)d_in[31], WH[8], WL[8], 2048, 512};

  float* bias_cat = (float*)alloc(2048 * 4);

  // --- regions -------------------------------------------------------------
  const size_t E_BSD = 8192ull * 512;
  char* R_A = (char*)alloc(E_BSD * 4);              // x planes -> sa_ctx -> umax -> out1
  char* R_B = (char*)alloc(E_BSD * 16);             // 4 parts
  __bf16* spanh = (__bf16*)alloc(1536ull * 768 * 2);
  __bf16* spanl = (__bf16*)alloc(1536ull * 768 * 2);
  __bf16* embh  = (__bf16*)alloc(1536ull * 512 * 2);
  __bf16* embl  = (__bf16*)alloc(1536ull * 512 * 2);
  float*  v_ca  = (float*)alloc(1536ull * 512 * 4);
  if (ws_size < off) return;   // fail visibly, not fault

  // R_A: x_norm planes -> sa_ctx planes -> umax (u32) -> out1 f32
  __bf16* xh = (__bf16*)R_A;   __bf16* xl = xh + E_BSD;
  __bf16* sh = xh;             __bf16* sl = xl;     // sa_ctx planes (x dead)
  unsigned* umax = (unsigned*)R_A;
  float* out1 = (float*)R_A;
  // R_B parts (16.78 MB each):
  //  p0: Q planes -> ctxA planes -> inter(lo half)
  //  p1: K planes -> attn planes -> inter(hi half)
  //  p2: VT planes -> ctx planes
  //  p3: caQ f32 -> y planes
  __bf16* Qh_g = (__bf16*)R_B;                    __bf16* Ql_g = Qh_g + E_BSD;
  __bf16* Kh_g = (__bf16*)(R_B + E_BSD * 4);      __bf16* Kl_g = Kh_g + E_BSD;
  __bf16* VTh_g = (__bf16*)(R_B + E_BSD * 8);     __bf16* VTl_g = VTh_g + E_BSD;
  float*  caQ  = (float*)(R_B + E_BSD * 12);
  __bf16* cah = (__bf16*)R_B;                     __bf16* cal = cah + E_BSD;
  __bf16* ah_pl = (__bf16*)(R_B + E_BSD * 4);     __bf16* al_pl = ah_pl + E_BSD;
  __bf16* cth   = (__bf16*)(R_B + E_BSD * 8);     __bf16* ctl   = cth + E_BSD;
  __bf16* yh    = (__bf16*)(R_B + E_BSD * 12);    __bf16* yl    = yh + E_BSD;
  __bf16* ih    = (__bf16*)R_B;                   __bf16* il    = ih + 4096ull * 2048;
  float* k_ca = (float*)spanh;                    // span planes dead by then
  float* dout = (float*)d_out;
  const int KBIG = 1 << 30;
  const float* Z = nullptr;
  const __bf16* ZB = nullptr;
  __bf16* ZM = nullptr;

  auto gemm = [&](int EPI, const __bf16* a0h, const __bf16* a0l,
                  const __bf16* a1h, const __bf16* a1l, int lda, int ksplit,
                  int wi, int K, const float* bias,
                  float* cf, __bf16* chp, __bf16* clp,
                  __bf16* c2h, __bf16* c2l, __bf16* c3h, __bf16* c3l,
                  int ldc, size_t secs,
                  const __bf16* E0h, const __bf16* E0l,
                  const __bf16* E1h, const __bf16* E1l, const float* E2,
                  int M, int N, const int* cmap, const int* cmask, int c0) {
    dim3 grid(N / 128, M / 128);
    switch (EPI) {
      case 0: gemm2_kernel<0><<<grid, 512, 0, stream>>>(a0h, a0l, a1h, a1l, lda, ksplit, WH[wi], WL[wi], K, bias, cf, chp, clp, c2h, c2l, c3h, c3l, ldc, secs, E0h, E0l, E1h, E1l, E2, cmap, cmask, c0); break;
      case 1: gemm2_kernel<1><<<grid, 512, 0, stream>>>(a0h, a0l, a1h, a1l, lda, ksplit, WH[wi], WL[wi], K, bias, cf, chp, clp, c2h, c2l, c3h, c3l, ldc, secs, E0h, E0l, E1h, E1l, E2, cmap, cmask, c0); break;
      case 2: gemm2_kernel<2><<<grid, 512, 0, stream>>>(a0h, a0l, a1h, a1l, lda, ksplit, WH[wi], WL[wi], K, bias, cf, chp, clp, c2h, c2l, c3h, c3l, ldc, secs, E0h, E0l, E1h, E1l, E2, cmap, cmask, c0); break;
      case 3: gemm2_kernel<3><<<grid, 512, 0, stream>>>(a0h, a0l, a1h, a1l, lda, ksplit, WH[wi], WL[wi], K, bias, cf, chp, clp, c2h, c2l, c3h, c3l, ldc, secs, E0h, E0l, E1h, E1l, E2, cmap, cmask, c0); break;
      case 4: gemm2_kernel<4><<<grid, 512, 0, stream>>>(a0h, a0l, a1h, a1l, lda, ksplit, WH[wi], WL[wi], K, bias, cf, chp, clp, c2h, c2l, c3h, c3l, ldc, secs, E0h, E0l, E1h, E1l, E2, cmap, cmask, c0); break;
      case 5: gemm2_kernel<5><<<grid, 512, 0, stream>>>(a0h, a0l, a1h, a1l, lda, ksplit, WH[wi], WL[wi], K, bias, cf, chp, clp, c2h, c2l, c3h, c3l, ldc, secs, E0h, E0l, E1h, E1l, E2, cmap, cmask, c0); break;
      case 6: gemm2_kernel<6><<<grid, 512, 0, stream>>>(a0h, a0l, a1h, a1l, lda, ksplit, WH[wi], WL[wi], K, bias, cf, chp, clp, c2h, c2l, c3h, c3l, ldc, secs, E0h, E0l, E1h, E1l, E2, cmap, cmask, c0); break;
    }
  };

  prep_weights_kernel<<<dim3(64, 12), 256, 0, stream>>>(pack);
  bias_cat_kernel<<<8, 256, 0, stream>>>(sa_bq, sa_bk, sa_bv, ca_bq, bias_cat);
  split_kernel<<<1152, 256, 0, stream>>>(span, spanh, spanl, 1536 * 768 / 4);
  ln_split_kernel<<<2048, 256, 0, stream>>>(inputs, ln_g, ln_b, xh, xl);

  // fused QKV + CA-Q projection
  gemm(5, xh, xl, xh, xl, 512, KBIG, 0, 512, bias_cat,
       caQ, Qh_g, Ql_g, Kh_g, Kl_g, VTh_g, VTl_g, 512, 0,
       ZB, ZB, ZB, ZB, Z, 8192, 2048, nullptr, nullptr, 0);

  // sa_ctx planes (sh/sl) live in R_A — xh/xl are dead after the QKVQ gemm.
  sa_attn_mfma_kernel<<<dim3(8, 8, 16), 256, 0, stream>>>(
      Qh_g, Ql_g, Kh_g, Kl_g, VTh_g, VTl_g, attn_mask, sh, sl);
  // sa_wo -> attn planes (p1; K planes dead)
  gemm(1, sh, sl, sh, sl, 512, KBIG, 4, 512, sa_bo,
       nullptr, ah_pl, al_pl, ZM, ZM, ZM, ZM, 512, 0, ZB, ZB, ZB, ZB, Z,
       8192, 512, nullptr, nullptr, 0);
  // umax init (R_A; sa_ctx planes consumed by sa_wo gemm above)
  fill_umax_kernel<<<4096, 256, 0, stream>>>(umax);

  // cross-attention K/V precompute
  gemm(1, spanh, spanl, spanh, spanl, 768, KBIG, 1, 768, lc_b,
       nullptr, embh, embl, ZM, ZM, ZM, ZM, 512, 0, ZB, ZB, ZB, ZB, Z,
       1536, 512, nullptr, nullptr, 0);
  gemm(0, embh, embl, embh, embl, 512, KBIG, 2, 512, ca_bk,
       k_ca, nullptr, nullptr, ZM, ZM, ZM, ZM, 512, 0, ZB, ZB, ZB, ZB, Z,
       1536, 512, nullptr, nullptr, 0);
  gemm(0, embh, embl, embh, embl, 512, KBIG, 3, 512, ca_bv,
       v_ca, nullptr, nullptr, ZM, ZM, ZM, ZM, 512, 0, ZB, ZB, ZB, ZB, Z,
       1536, 512, nullptr, nullptr, 0);

  // CA in 8 chunks of 16 chains; ca_wo gemm folds segment-max via atomics
  for (int chk = 0; chk < 8; chk++) {
    const int c0 = chk * 16;
    ca_attn_kernel<<<dim3(16, 16), 256, 0, stream>>>(caQ, k_ca, v_ca, chain_map, chain_mask, cah, cal, c0);
    gemm(6, cah, cal, cah, cal, 512, KBIG, 5, 512, ca_bo,
         (float*)umax, nullptr, nullptr, ZM, ZM, ZM, ZM, 512, 0,
         ZB, ZB, ZB, ZB, Z, 8192, 512, chain_map, chain_mask, c0);
  }
  decode_umax_kernel<<<4096, 256, 0, stream>>>(umax, cth, ctl);

  // gate: A = [attn planes | ctx planes], epilogue z*a+(1-z)*c+inputs -> out1
  gemm(3, ah_pl, al_pl, cth, ctl, 512, 512, 6, 1024, g_b,
       out1, nullptr, nullptr, ZM, ZM, ZM, ZM, 512, 0,
       ah_pl, al_pl, cth, ctl, inputs, 8192, 512, nullptr, nullptr, 0);

  // feed-forward
  ln_split_kernel<<<2048, 256, 0, stream>>>(out1, ff_ln_g, ff_ln_b, yh, yl);
  for (int r0 = 0; r0 < 8192; r0 += 4096) {
    gemm(2, yh + (size_t)r0 * 512, yl + (size_t)r0 * 512,
         yh + (size_t)r0 * 512, yl + (size_t)r0 * 512, 512, KBIG, 7, 512, ff_b1,
         nullptr, ih, il, ZM, ZM, ZM, ZM, 2048, 512, ZB, ZB, ZB, ZB, Z,
         4096, 2048, nullptr, nullptr, 0);
    gemm(4, ih, il, ih, il, 2048, KBIG, 8, 2048, ff_b2,
         dout + (size_t)r0 * 512, nullptr, nullptr, ZM, ZM, ZM, ZM, 512, 0,
         ZB, ZB, ZB, ZB, out1 + (size_t)r0 * 512, 4096, 512, nullptr, nullptr, 0);
  }
}